// Round 11
// baseline (102.520 us; speedup 1.0000x reference)
//
#include <hip/hip_runtime.h>
#include <math.h>

#define N_PTS 20000
#define M_ATM 8000
#define DD    16
#define KK    16
#define HH    33
#define BB    4
#define EPSGN 1e-5f
#define SLOPE 0.2f
#define SLOTS 36          // 36*64 = 2304 candidate slots per batch
#define PSLOT 2304
#define SENT  0xFFFFFFFFu // > any real key (real off <= 2303 < 0xFFF)

// packed layout per layer (floats): wx[33][20] | wb[33][16] | wt[33][16]
#define PK_WX   0
#define PK_WB   660
#define PK_WT   1188
#define PK_LAY  1716

// ws layout (bytes)
#define WS_PAD   0                      // 4*2304*16 = 147456 (padded f32 atom table)
#define WS_SEG   147456                 // 8 ints
#define WS_WP    147520                 // 3*1716 floats -> ends 168112
#define WS_IDX   168128                 // N*K ints
#define WS_D2    (168128 + 1280000)     // N*K floats

// ---------------- repack: weights + padded f32 atom table + batch boundaries ----
__global__ void repack_kernel(const float* __restrict__ W1, const float* __restrict__ b1,
                              const float* __restrict__ W2,
                              const float* __restrict__ y, const int* __restrict__ yb,
                              float* __restrict__ wp, float* __restrict__ ypad,
                              int* __restrict__ seg)
{
    const int tid = blockIdx.x*256 + threadIdx.x;
    const int stride = gridDim.x*256;

    for (int i = tid; i < 3*PK_LAY; i += stride) {
        const int L = i / PK_LAY, r = i % PK_LAY;
        float v;
        if (r < PK_WB) {                    // wx[o][20] = W1a(16) | b1 | w_dist | pad2
            const int o = r / 20, c = r % 20;
            if      (c < 16)  v = W1[(L*HH + o)*HH + c];
            else if (c == 16) v = b1[L*HH + o];
            else if (c == 17) v = W1[(L*HH + o)*HH + 32];
            else              v = 0.0f;
        } else if (r < PK_WT) {             // wb[o][16] = W1[o][16..31]
            const int q = r - PK_WB, o = q / 16, c = q % 16;
            v = W1[(L*HH + o)*HH + 16 + c];
        } else {                            // wt[o][16] = W2[d][o] transposed
            const int q = r - PK_WT, o = q / 16, d = q % 16;
            v = W2[(L*DD + d)*HH + o];
        }
        wp[i] = v;
    }

    // padded candidate table: [b][slot] = (-2y0,-2y1,-2y2,|y|^2), pad = +inf
    for (int p = tid; p < BB*PSLOT; p += stride) {
        const int b = p / PSLOT, o = p % PSLOT;
        int l = 0, r = M_ATM;
        while (l < r) { int m = (l+r) >> 1; if (yb[m] <  b) l = m+1; else r = m; }
        const int lo = l;
        l = 0; r = M_ATM;
        while (l < r) { int m = (l+r) >> 1; if (yb[m] <= b) l = m+1; else r = m; }
        const int hi = l;
        float4 v;
        const int j = lo + o;
        if (j < hi) {
            const double y0 = (double)y[j*3+0];
            const double y1 = (double)y[j*3+1];
            const double y2 = (double)y[j*3+2];
            v = make_float4((float)(-2.0*y0), (float)(-2.0*y1), (float)(-2.0*y2),
                            (float)(y0*y0 + y1*y1 + y2*y2));
        } else {
            v = make_float4(0.0f, 0.0f, 0.0f, __builtin_inff());
        }
        reinterpret_cast<float4*>(ypad)[p] = v;
    }

    for (int j = tid; j < M_ATM; j += stride) {
        const int bcur  = yb[j];
        const int bprev = (j == 0) ? -1 : yb[j-1];
        for (int t = bprev+1; t <= bcur; ++t) seg[t] = j;
        if (j == M_ATM-1) { for (int t = bcur+1; t <= BB; ++t) seg[t] = M_ATM; }
    }
}

__device__ __forceinline__ unsigned wave_min_u32(unsigned v) {
    #define SW(OFF) { const unsigned o = (unsigned)__builtin_amdgcn_ds_swizzle((int)v, OFF); v = (o < v) ? o : v; }
    SW(0x041F) SW(0x081F) SW(0x101F) SW(0x201F) SW(0x401F)
    #undef SW
    { const unsigned o = (unsigned)__shfl_xor((int)v, 32); v = (o < v) ? o : v; }
    return v;
}

// ---------------- KNN: one WAVE per point, u32 truncated-key selection ----------
__global__ __launch_bounds__(256) void knn_kernel(
    const float* __restrict__ x, const int* __restrict__ xb,
    const float* __restrict__ ypad, const int* __restrict__ seg,
    const float* __restrict__ yg,
    int* __restrict__ out_idx, float* __restrict__ out_d2)
{
    const int wv   = threadIdx.x >> 6;
    const int lane = threadIdx.x & 63;
    const int n    = blockIdx.x * 4 + wv;

    const float xf0 = x[n*3+0], xf1 = x[n*3+1], xf2 = x[n*3+2];
    const float sxf = fmaf(xf0, xf0, fmaf(xf1, xf1, xf2*xf2));
    const int b  = xb[n];
    const int lo = seg[b];
    const float4* __restrict__ base =
        reinterpret_cast<const float4*>(ypad) + b*PSLOT + lane;

    // per-lane sorted top-4 keys via unconditional min/max network
    unsigned m0 = SENT, m1 = SENT, m2 = SENT, m3 = SENT;
    #pragma unroll
    for (int s = 0; s < SLOTS; ++s) {
        const float4 q = base[64*s];
        float dd = fmaf(xf2, q.z, fmaf(xf1, q.y, fmaf(xf0, q.x, sxf + q.w)));
        dd = fmaxf(dd, 0.0f);
        const unsigned kb = (__float_as_uint(dd) & 0xFFFFF000u)
                          | (unsigned)(lane | (s << 6));
        const unsigned a0 = min(m0, kb), c0 = max(m0, kb);
        const unsigned a1 = min(m1, c0), c1 = max(m1, c0);
        const unsigned a2 = min(m2, c1), c2 = max(m2, c1);
        const unsigned a3 = min(m3, c2);
        m0 = a0; m1 = a1; m2 = a2; m3 = a3;
    }

    unsigned long long cmask = 0ull;   // consumed slots (for rare rebuild)
    unsigned res_key = 0, h16 = 0;

    #define POPWIN(H)                                                         \
        if (lane == ((H) & 63u)) {                                            \
            cmask |= 1ull << (((H) >> 6) & 63u);                              \
            m0 = m1; m1 = m2; m2 = m3; m3 = SENT;                             \
            if (m0 == SENT) {                                                 \
                _Pragma("unroll 1")                                           \
                for (int s2 = 0; s2 < SLOTS; ++s2) {                          \
                    const float4 q2 = base[64*s2];                            \
                    float d2f = fmaf(xf2, q2.z, fmaf(xf1, q2.y,               \
                                 fmaf(xf0, q2.x, sxf + q2.w)));               \
                    d2f = fmaxf(d2f, 0.0f);                                   \
                    unsigned kb2 = (__float_as_uint(d2f) & 0xFFFFF000u)       \
                                 | (unsigned)(lane | (s2 << 6));              \
                    if ((cmask >> s2) & 1ull) kb2 = SENT;                     \
                    const unsigned a0 = min(m0, kb2), c0 = max(m0, kb2);      \
                    const unsigned a1 = min(m1, c0), c1 = max(m1, c0);        \
                    const unsigned a2 = min(m2, c1), c2 = max(m2, c1);        \
                    const unsigned a3 = min(m3, c2);                          \
                    m0 = a0; m1 = a1; m2 = a2; m3 = a3;                       \
                }                                                             \
            }                                                                 \
        }

    for (int r = 0; r < KK; ++r) {
        const unsigned h = wave_min_u32(m0);   // wave-uniform winner key
        if (lane == r) res_key = h;
        h16 = h;
        POPWIN(h)
    }

    // margin extras: truncation (2^-11 rel) + f32 eval error coverage
    int e = 0;
    {
        const float d16t = __uint_as_float(h16 & 0xFFFFF000u);
        const unsigned limbits = __float_as_uint(fmaf(d16t, 1.0025f, 0.01f));
        while (e < 8) {
            const unsigned h = wave_min_u32(m0);
            if ((h & 0xFFFFF000u) > limbits) break;
            if (lane == KK + e) res_key = h;
            POPWIN(h)
            ++e;
        }
    }
    #undef POPWIN

    // finalize: exact f64 distances for the 16+e survivors
    const int nact = KK + e;
    const bool have = (lane < nact);
    const unsigned off = res_key & 0xFFFu;
    double dd64 = 0.0;
    if (have) {
        const int j = lo + (int)off;
        const double yy0 = (double)yg[j*3+0];
        const double yy1 = (double)yg[j*3+1];
        const double yy2 = (double)yg[j*3+2];
        const double xd0 = (double)xf0, xd1 = (double)xf1, xd2 = (double)xf2;
        const double sxd = fma(xd0, xd0, fma(xd1, xd1, xd2*xd2));
        const double syd = fma(yy0, yy0, fma(yy1, yy1, yy2*yy2));
        dd64 = fma(xd2, -2.0*yy2, fma(xd1, -2.0*yy1, fma(xd0, -2.0*yy0, sxd + syd)));
        dd64 = fmax(dd64, 0.0);
    }

    if (e == 0) {
        if (have) {
            out_idx[n*KK + lane] = lo + (int)off;
            out_d2 [n*KK + lane] = (float)dd64;
        }
    } else {
        const unsigned long long fkey = have
            ? (((unsigned long long)__double_as_longlong(dd64) & ~0xFFFull) | off)
            : 0xFFFFFFFFFFFFFFFFull;
        int rank = 0;
        #pragma unroll 1
        for (int t = 0; t < nact; ++t) {
            const unsigned klo = (unsigned)__builtin_amdgcn_readlane((int)(unsigned)fkey, t);
            const unsigned khi = (unsigned)__builtin_amdgcn_readlane((int)(unsigned)(fkey >> 32), t);
            const unsigned long long kt = ((unsigned long long)khi << 32) | klo;
            rank += (kt < fkey) ? 1 : 0;
        }
        if (have && rank < KK) {
            out_idx[n*KK + rank] = lo + (int)off;
            out_d2 [n*KK + rank] = (float)dd64;
        }
    }
}

// ---------------- MP: 8 lanes/point, 2 k's/lane, ping-pong pipelined o-loop ----
#define DOT16(res, A, q0, q1, q2, q3) {                                 \
    float _e = res, _o = 0.0f;                                          \
    _e = fmaf(A[0],  q0.x, _e); _o = fmaf(A[1],  q0.y, _o);             \
    _e = fmaf(A[2],  q0.z, _e); _o = fmaf(A[3],  q0.w, _o);             \
    _e = fmaf(A[4],  q1.x, _e); _o = fmaf(A[5],  q1.y, _o);             \
    _e = fmaf(A[6],  q1.z, _e); _o = fmaf(A[7],  q1.w, _o);             \
    _e = fmaf(A[8],  q2.x, _e); _o = fmaf(A[9],  q2.y, _o);             \
    _e = fmaf(A[10], q2.z, _e); _o = fmaf(A[11], q2.w, _o);             \
    _e = fmaf(A[12], q3.x, _e); _o = fmaf(A[13], q3.y, _o);             \
    _e = fmaf(A[14], q3.z, _e); _o = fmaf(A[15], q3.w, _o);             \
    res = _e + _o; }

// load weight row O into register set P (13 float4); names use P##_N to keep
// the preprocessor from lexing "N.x" as one pp-number token
#define LDW(P, O) {                                                     \
    P##_0  = wxp[(O)*5+0]; P##_1  = wxp[(O)*5+1]; P##_2  = wxp[(O)*5+2];\
    P##_3  = wxp[(O)*5+3]; P##_4  = wxp[(O)*5+4];                       \
    P##_5  = wbp[(O)*4+0]; P##_6  = wbp[(O)*4+1]; P##_7  = wbp[(O)*4+2];\
    P##_8  = wbp[(O)*4+3];                                              \
    P##_9  = wtp[(O)*4+0]; P##_10 = wtp[(O)*4+1]; P##_11 = wtp[(O)*4+2];\
    P##_12 = wtp[(O)*4+3]; }

// compute one hidden unit from register set P
#define CMPW(P) {                                                       \
    float bas = P##_4.x;                                                \
    DOT16(bas, pe, P##_0, P##_1, P##_2, P##_3);                         \
    float u0 = fmaf(dv.x, P##_4.y, bas);                                \
    DOT16(u0, at0, P##_5, P##_6, P##_7, P##_8);                         \
    float u1 = fmaf(dv.y, P##_4.y, bas);                                \
    DOT16(u1, at1, P##_5, P##_6, P##_7, P##_8);                         \
    const float hs = fmaxf(u0, SLOPE*u0) + fmaxf(u1, SLOPE*u1);         \
    msg[0]  = fmaf(hs, P##_9.x,  msg[0]);  msg[1]  = fmaf(hs, P##_9.y,  msg[1]);  \
    msg[2]  = fmaf(hs, P##_9.z,  msg[2]);  msg[3]  = fmaf(hs, P##_9.w,  msg[3]);  \
    msg[4]  = fmaf(hs, P##_10.x, msg[4]);  msg[5]  = fmaf(hs, P##_10.y, msg[5]);  \
    msg[6]  = fmaf(hs, P##_10.z, msg[6]);  msg[7]  = fmaf(hs, P##_10.w, msg[7]);  \
    msg[8]  = fmaf(hs, P##_11.x, msg[8]);  msg[9]  = fmaf(hs, P##_11.y, msg[9]);  \
    msg[10] = fmaf(hs, P##_11.z, msg[10]); msg[11] = fmaf(hs, P##_11.w, msg[11]); \
    msg[12] = fmaf(hs, P##_12.x, msg[12]); msg[13] = fmaf(hs, P##_12.y, msg[13]); \
    msg[14] = fmaf(hs, P##_12.z, msg[14]); msg[15] = fmaf(hs, P##_12.w, msg[15]); }

__global__ __launch_bounds__(256) void mp_kernel(
    const int*   __restrict__ nidx, const float* __restrict__ nd2,
    const float* __restrict__ yat,  const float* __restrict__ wpack,
    const float* __restrict__ b2,
    const float* __restrict__ gnw, const float* __restrict__ gnb,
    float* __restrict__ out)
{
    const int g  = blockIdx.x * 256 + threadIdx.x;
    const int n  = g >> 3;
    const int kl = g & 7;

    const int2   iv = *reinterpret_cast<const int2*>  (nidx + n*KK + kl*2);
    const float2 dv = *reinterpret_cast<const float2*>(nd2  + n*KK + kl*2);

    float at0[DD], at1[DD];
    {
        const float4* p0 = reinterpret_cast<const float4*>(yat + (long)iv.x*DD);
        const float4* p1 = reinterpret_cast<const float4*>(yat + (long)iv.y*DD);
        const float4 a = p0[0], b = p0[1], c = p0[2], d = p0[3];
        const float4 e = p1[0], f = p1[1], h = p1[2], i = p1[3];
        at0[0]=a.x; at0[1]=a.y; at0[2]=a.z; at0[3]=a.w;
        at0[4]=b.x; at0[5]=b.y; at0[6]=b.z; at0[7]=b.w;
        at0[8]=c.x; at0[9]=c.y; at0[10]=c.z; at0[11]=c.w;
        at0[12]=d.x; at0[13]=d.y; at0[14]=d.z; at0[15]=d.w;
        at1[0]=e.x; at1[1]=e.y; at1[2]=e.z; at1[3]=e.w;
        at1[4]=f.x; at1[5]=f.y; at1[6]=f.z; at1[7]=f.w;
        at1[8]=h.x; at1[9]=h.y; at1[10]=h.z; at1[11]=h.w;
        at1[12]=i.x; at1[13]=i.y; at1[14]=i.z; at1[15]=i.w;
    }

    float pe[DD];
    #pragma unroll
    for (int h = 0; h < DD; ++h) pe[h] = 1.0f;

    for (int L = 0; L < 3; ++L) {
        const float4* wxp = reinterpret_cast<const float4*>(wpack + L*PK_LAY + PK_WX);
        const float4* wbp = reinterpret_cast<const float4*>(wpack + L*PK_LAY + PK_WB);
        const float4* wtp = reinterpret_cast<const float4*>(wpack + L*PK_LAY + PK_WT);

        float msg[DD];
        {
            const float4* bq = reinterpret_cast<const float4*>(b2 + L*DD);
            const float4 q0 = bq[0], q1 = bq[1], q2 = bq[2], q3 = bq[3];
            msg[0]=2.f*q0.x; msg[1]=2.f*q0.y; msg[2]=2.f*q0.z; msg[3]=2.f*q0.w;
            msg[4]=2.f*q1.x; msg[5]=2.f*q1.y; msg[6]=2.f*q1.z; msg[7]=2.f*q1.w;
            msg[8]=2.f*q2.x; msg[9]=2.f*q2.y; msg[10]=2.f*q2.z; msg[11]=2.f*q2.w;
            msg[12]=2.f*q3.x; msg[13]=2.f*q3.y; msg[14]=2.f*q3.z; msg[15]=2.f*q3.w;
        }

        // ping-pong software pipeline over o = 0..32
        float4 pA_0,pA_1,pA_2,pA_3,pA_4,pA_5,pA_6,pA_7,pA_8,pA_9,pA_10,pA_11,pA_12;
        float4 pB_0,pB_1,pB_2,pB_3,pB_4,pB_5,pB_6,pB_7,pB_8,pB_9,pB_10,pB_11,pB_12;
        LDW(pA, 0)
        #pragma unroll 1
        for (int o = 0; o < 32; o += 2) {
            LDW(pB, o+1)     // issue o+1 loads; latency hides under CMPW(pA)
            CMPW(pA)
            LDW(pA, o+2)     // o+2 <= 32 always valid
            CMPW(pB)
        }
        CMPW(pA)             // o = 32

        // sum partial msg over the 8 lanes of this point
        #pragma unroll
        for (int o = 0; o < DD; ++o) {
            msg[o] += __shfl_xor(msg[o], 1);
            msg[o] += __shfl_xor(msg[o], 2);
            msg[o] += __shfl_xor(msg[o], 4);
        }

        // GroupNorm(2,16) + leaky + residual (redundant per lane)
        const float4* gw = reinterpret_cast<const float4*>(gnw + L*DD);
        const float4* gb = reinterpret_cast<const float4*>(gnb + L*DD);
        const float4 gw0 = gw[0], gw1 = gw[1], gw2 = gw[2], gw3 = gw[3];
        const float4 gb0 = gb[0], gb1 = gb[1], gb2 = gb[2], gb3 = gb[3];
        const float gwa[DD] = { gw0.x,gw0.y,gw0.z,gw0.w, gw1.x,gw1.y,gw1.z,gw1.w,
                                gw2.x,gw2.y,gw2.z,gw2.w, gw3.x,gw3.y,gw3.z,gw3.w };
        const float gba[DD] = { gb0.x,gb0.y,gb0.z,gb0.w, gb1.x,gb1.y,gb1.z,gb1.w,
                                gb2.x,gb2.y,gb2.z,gb2.w, gb3.x,gb3.y,gb3.z,gb3.w };
        #pragma unroll
        for (int grp = 0; grp < 2; ++grp) {
            float mu = 0.0f;
            #pragma unroll
            for (int j = 0; j < 8; ++j) mu += msg[grp*8 + j];
            mu *= 0.125f;
            float var = 0.0f;
            #pragma unroll
            for (int j = 0; j < 8; ++j) { const float d = msg[grp*8 + j] - mu; var = fmaf(d, d, var); }
            var *= 0.125f;
            const float rs = rsqrtf(var + EPSGN);
            #pragma unroll
            for (int j = 0; j < 8; ++j) {
                const int c = grp*8 + j;
                const float v = (msg[c] - mu) * rs * gwa[c] + gba[c];
                pe[c] += fmaxf(v, SLOPE * v);
            }
        }
    }

    if (kl == 0) {
        float4* op = reinterpret_cast<float4*>(out + (long)n*DD);
        op[0] = make_float4(pe[0],  pe[1],  pe[2],  pe[3]);
        op[1] = make_float4(pe[4],  pe[5],  pe[6],  pe[7]);
        op[2] = make_float4(pe[8],  pe[9],  pe[10], pe[11]);
        op[3] = make_float4(pe[12], pe[13], pe[14], pe[15]);
    }
}

extern "C" void kernel_launch(void* const* d_in, const int* in_sizes, int n_in,
                              void* d_out, int out_size, void* d_ws, size_t ws_size,
                              hipStream_t stream) {
    const float* x   = (const float*)d_in[0];
    const float* y   = (const float*)d_in[1];
    const float* yat = (const float*)d_in[2];
    const int*   xb  = (const int*)  d_in[3];
    const int*   yb  = (const int*)  d_in[4];
    const float* W1  = (const float*)d_in[5];
    const float* b1  = (const float*)d_in[6];
    const float* W2  = (const float*)d_in[7];
    const float* b2  = (const float*)d_in[8];
    const float* gnw = (const float*)d_in[9];
    const float* gnb = (const float*)d_in[10];
    float* out = (float*)d_out;

    float* ypad   = (float*)((char*)d_ws + WS_PAD);
    int*   seg    = (int*)  ((char*)d_ws + WS_SEG);
    float* wpack  = (float*)((char*)d_ws + WS_WP);
    int*   ws_idx = (int*)  ((char*)d_ws + WS_IDX);
    float* ws_d2  = (float*)((char*)d_ws + WS_D2);

    repack_kernel<<<16, 256, 0, stream>>>(W1, b1, W2, y, yb, wpack, ypad, seg);
    knn_kernel<<<N_PTS/4, 256, 0, stream>>>(x, xb, ypad, seg, y, ws_idx, ws_d2);
    mp_kernel<<<(N_PTS*8)/256, 256, 0, stream>>>(
        ws_idx, ws_d2, yat, wpack, b2, gnw, gnb, out);
}

// Round 12
// 93.000 us; speedup vs baseline: 1.1024x; 1.1024x over previous
//
#include <hip/hip_runtime.h>
#include <math.h>

#define N_PTS 20000
#define M_ATM 8000
#define DD    16
#define KK    16
#define HH    33
#define BB    4
#define EPSGN 1e-5f
#define SLOPE 0.2f
#define SLOTS 36          // 36*64 = 2304 candidate slots per batch
#define PSLOT 2304
#define SENT  0xFFFFFFFFu // > any real key (real off <= 2303 < 0xFFF)

// packed layout per layer (floats): wx[33][20] | wb[33][16] | wt[33][16]
#define PK_WX   0
#define PK_WB   660
#define PK_WT   1188
#define PK_LAY  1716
// same offsets in float4 units
#define Q_WX    0
#define Q_WB    165
#define Q_WT    297
#define Q_LAY   429

// ws layout (bytes)
#define WS_PAD   0                      // 4*2304*16 = 147456 (padded f32 atom table)
#define WS_SEG   147456                 // 8 ints
#define WS_WP    147520                 // 3*1716 floats -> ends 168112
#define WS_IDX   168128                 // N*K ints
#define WS_D2    (168128 + 1280000)     // N*K floats

// ---------------- repack: weights + padded f32 atom table + batch boundaries ----
__global__ void repack_kernel(const float* __restrict__ W1, const float* __restrict__ b1,
                              const float* __restrict__ W2,
                              const float* __restrict__ y, const int* __restrict__ yb,
                              float* __restrict__ wp, float* __restrict__ ypad,
                              int* __restrict__ seg)
{
    const int tid = blockIdx.x*256 + threadIdx.x;
    const int stride = gridDim.x*256;

    for (int i = tid; i < 3*PK_LAY; i += stride) {
        const int L = i / PK_LAY, r = i % PK_LAY;
        float v;
        if (r < PK_WB) {                    // wx[o][20] = W1a(16) | b1 | w_dist | pad2
            const int o = r / 20, c = r % 20;
            if      (c < 16)  v = W1[(L*HH + o)*HH + c];
            else if (c == 16) v = b1[L*HH + o];
            else if (c == 17) v = W1[(L*HH + o)*HH + 32];
            else              v = 0.0f;
        } else if (r < PK_WT) {             // wb[o][16] = W1[o][16..31]
            const int q = r - PK_WB, o = q / 16, c = q % 16;
            v = W1[(L*HH + o)*HH + 16 + c];
        } else {                            // wt[o][16] = W2[d][o] transposed
            const int q = r - PK_WT, o = q / 16, d = q % 16;
            v = W2[(L*DD + d)*HH + o];
        }
        wp[i] = v;
    }

    // padded candidate table: [b][slot] = (-2y0,-2y1,-2y2,|y|^2), pad = +inf
    for (int p = tid; p < BB*PSLOT; p += stride) {
        const int b = p / PSLOT, o = p % PSLOT;
        int l = 0, r = M_ATM;
        while (l < r) { int m = (l+r) >> 1; if (yb[m] <  b) l = m+1; else r = m; }
        const int lo = l;
        l = 0; r = M_ATM;
        while (l < r) { int m = (l+r) >> 1; if (yb[m] <= b) l = m+1; else r = m; }
        const int hi = l;
        float4 v;
        const int j = lo + o;
        if (j < hi) {
            const double y0 = (double)y[j*3+0];
            const double y1 = (double)y[j*3+1];
            const double y2 = (double)y[j*3+2];
            v = make_float4((float)(-2.0*y0), (float)(-2.0*y1), (float)(-2.0*y2),
                            (float)(y0*y0 + y1*y1 + y2*y2));
        } else {
            v = make_float4(0.0f, 0.0f, 0.0f, __builtin_inff());
        }
        reinterpret_cast<float4*>(ypad)[p] = v;
    }

    for (int j = tid; j < M_ATM; j += stride) {
        const int bcur  = yb[j];
        const int bprev = (j == 0) ? -1 : yb[j-1];
        for (int t = bprev+1; t <= bcur; ++t) seg[t] = j;
        if (j == M_ATM-1) { for (int t = bcur+1; t <= BB; ++t) seg[t] = M_ATM; }
    }
}

__device__ __forceinline__ unsigned wave_min_u32(unsigned v) {
    #define SW(OFF) { const unsigned o = (unsigned)__builtin_amdgcn_ds_swizzle((int)v, OFF); v = (o < v) ? o : v; }
    SW(0x041F) SW(0x081F) SW(0x101F) SW(0x201F) SW(0x401F)
    #undef SW
    { const unsigned o = (unsigned)__shfl_xor((int)v, 32); v = (o < v) ? o : v; }
    return v;
}

// ---------------- KNN: one WAVE per point, u32 truncated-key selection ----------
__global__ __launch_bounds__(256) void knn_kernel(
    const float* __restrict__ x, const int* __restrict__ xb,
    const float* __restrict__ ypad, const int* __restrict__ seg,
    const float* __restrict__ yg,
    int* __restrict__ out_idx, float* __restrict__ out_d2)
{
    const int wv   = threadIdx.x >> 6;
    const int lane = threadIdx.x & 63;
    const int n    = blockIdx.x * 4 + wv;

    const float xf0 = x[n*3+0], xf1 = x[n*3+1], xf2 = x[n*3+2];
    const float sxf = fmaf(xf0, xf0, fmaf(xf1, xf1, xf2*xf2));
    const int b  = xb[n];
    const int lo = seg[b];
    const float4* __restrict__ base =
        reinterpret_cast<const float4*>(ypad) + b*PSLOT + lane;

    // per-lane sorted top-4 keys via unconditional min/max network
    unsigned m0 = SENT, m1 = SENT, m2 = SENT, m3 = SENT;
    #pragma unroll
    for (int s = 0; s < SLOTS; ++s) {
        const float4 q = base[64*s];
        float dd = fmaf(xf2, q.z, fmaf(xf1, q.y, fmaf(xf0, q.x, sxf + q.w)));
        dd = fmaxf(dd, 0.0f);
        const unsigned kb = (__float_as_uint(dd) & 0xFFFFF000u)
                          | (unsigned)(lane | (s << 6));
        const unsigned a0 = min(m0, kb), c0 = max(m0, kb);
        const unsigned a1 = min(m1, c0), c1 = max(m1, c0);
        const unsigned a2 = min(m2, c1), c2 = max(m2, c1);
        const unsigned a3 = min(m3, c2);
        m0 = a0; m1 = a1; m2 = a2; m3 = a3;
    }

    unsigned long long cmask = 0ull;   // consumed slots (for rare rebuild)
    unsigned res_key = 0, h16 = 0;

    #define POPWIN(H)                                                         \
        if (lane == ((H) & 63u)) {                                            \
            cmask |= 1ull << (((H) >> 6) & 63u);                              \
            m0 = m1; m1 = m2; m2 = m3; m3 = SENT;                             \
            if (m0 == SENT) {                                                 \
                _Pragma("unroll 1")                                           \
                for (int s2 = 0; s2 < SLOTS; ++s2) {                          \
                    const float4 q2 = base[64*s2];                            \
                    float d2f = fmaf(xf2, q2.z, fmaf(xf1, q2.y,               \
                                 fmaf(xf0, q2.x, sxf + q2.w)));               \
                    d2f = fmaxf(d2f, 0.0f);                                   \
                    unsigned kb2 = (__float_as_uint(d2f) & 0xFFFFF000u)       \
                                 | (unsigned)(lane | (s2 << 6));              \
                    if ((cmask >> s2) & 1ull) kb2 = SENT;                     \
                    const unsigned a0 = min(m0, kb2), c0 = max(m0, kb2);      \
                    const unsigned a1 = min(m1, c0), c1 = max(m1, c0);        \
                    const unsigned a2 = min(m2, c1), c2 = max(m2, c1);        \
                    const unsigned a3 = min(m3, c2);                          \
                    m0 = a0; m1 = a1; m2 = a2; m3 = a3;                       \
                }                                                             \
            }                                                                 \
        }

    for (int r = 0; r < KK; ++r) {
        const unsigned h = wave_min_u32(m0);   // wave-uniform winner key
        if (lane == r) res_key = h;
        h16 = h;
        POPWIN(h)
    }

    // margin extras: truncation (2^-11 rel) + f32 eval error coverage
    int e = 0;
    {
        const float d16t = __uint_as_float(h16 & 0xFFFFF000u);
        const unsigned limbits = __float_as_uint(fmaf(d16t, 1.0025f, 0.01f));
        while (e < 8) {
            const unsigned h = wave_min_u32(m0);
            if ((h & 0xFFFFF000u) > limbits) break;
            if (lane == KK + e) res_key = h;
            POPWIN(h)
            ++e;
        }
    }
    #undef POPWIN

    // finalize: exact f64 distances for the 16+e survivors
    const int nact = KK + e;
    const bool have = (lane < nact);
    const unsigned off = res_key & 0xFFFu;
    double dd64 = 0.0;
    if (have) {
        const int j = lo + (int)off;
        const double yy0 = (double)yg[j*3+0];
        const double yy1 = (double)yg[j*3+1];
        const double yy2 = (double)yg[j*3+2];
        const double xd0 = (double)xf0, xd1 = (double)xf1, xd2 = (double)xf2;
        const double sxd = fma(xd0, xd0, fma(xd1, xd1, xd2*xd2));
        const double syd = fma(yy0, yy0, fma(yy1, yy1, yy2*yy2));
        dd64 = fma(xd2, -2.0*yy2, fma(xd1, -2.0*yy1, fma(xd0, -2.0*yy0, sxd + syd)));
        dd64 = fmax(dd64, 0.0);
    }

    if (e == 0) {
        if (have) {
            out_idx[n*KK + lane] = lo + (int)off;
            out_d2 [n*KK + lane] = (float)dd64;
        }
    } else {
        const unsigned long long fkey = have
            ? (((unsigned long long)__double_as_longlong(dd64) & ~0xFFFull) | off)
            : 0xFFFFFFFFFFFFFFFFull;
        int rank = 0;
        #pragma unroll 1
        for (int t = 0; t < nact; ++t) {
            const unsigned klo = (unsigned)__builtin_amdgcn_readlane((int)(unsigned)fkey, t);
            const unsigned khi = (unsigned)__builtin_amdgcn_readlane((int)(unsigned)(fkey >> 32), t);
            const unsigned long long kt = ((unsigned long long)khi << 32) | klo;
            rank += (kt < fkey) ? 1 : 0;
        }
        if (have && rank < KK) {
            out_idx[n*KK + rank] = lo + (int)off;
            out_d2 [n*KK + rank] = (float)dd64;
        }
    }
}

// ---------------- MP: 8 lanes/point, weights in LDS, VGPR ping-pong o-loop ----
#define DOT16(res, A, q0, q1, q2, q3) {                                 \
    float _e = res, _o = 0.0f;                                          \
    _e = fmaf(A[0],  q0.x, _e); _o = fmaf(A[1],  q0.y, _o);             \
    _e = fmaf(A[2],  q0.z, _e); _o = fmaf(A[3],  q0.w, _o);             \
    _e = fmaf(A[4],  q1.x, _e); _o = fmaf(A[5],  q1.y, _o);             \
    _e = fmaf(A[6],  q1.z, _e); _o = fmaf(A[7],  q1.w, _o);             \
    _e = fmaf(A[8],  q2.x, _e); _o = fmaf(A[9],  q2.y, _o);             \
    _e = fmaf(A[10], q2.z, _e); _o = fmaf(A[11], q2.w, _o);             \
    _e = fmaf(A[12], q3.x, _e); _o = fmaf(A[13], q3.y, _o);             \
    _e = fmaf(A[14], q3.z, _e); _o = fmaf(A[15], q3.w, _o);             \
    res = _e + _o; }

// load weight row O into VGPR set P (13 float4) from LDS
#define LDW(P, O) {                                                     \
    P##_0  = wxp[(O)*5+0]; P##_1  = wxp[(O)*5+1]; P##_2  = wxp[(O)*5+2];\
    P##_3  = wxp[(O)*5+3]; P##_4  = wxp[(O)*5+4];                       \
    P##_5  = wbp[(O)*4+0]; P##_6  = wbp[(O)*4+1]; P##_7  = wbp[(O)*4+2];\
    P##_8  = wbp[(O)*4+3];                                              \
    P##_9  = wtp[(O)*4+0]; P##_10 = wtp[(O)*4+1]; P##_11 = wtp[(O)*4+2];\
    P##_12 = wtp[(O)*4+3]; }

// compute one hidden unit from register set P
#define CMPW(P) {                                                       \
    float bas = P##_4.x;                                                \
    DOT16(bas, pe, P##_0, P##_1, P##_2, P##_3);                         \
    float u0 = fmaf(dv.x, P##_4.y, bas);                                \
    DOT16(u0, at0, P##_5, P##_6, P##_7, P##_8);                         \
    float u1 = fmaf(dv.y, P##_4.y, bas);                                \
    DOT16(u1, at1, P##_5, P##_6, P##_7, P##_8);                         \
    const float hs = fmaxf(u0, SLOPE*u0) + fmaxf(u1, SLOPE*u1);         \
    msg[0]  = fmaf(hs, P##_9.x,  msg[0]);  msg[1]  = fmaf(hs, P##_9.y,  msg[1]);  \
    msg[2]  = fmaf(hs, P##_9.z,  msg[2]);  msg[3]  = fmaf(hs, P##_9.w,  msg[3]);  \
    msg[4]  = fmaf(hs, P##_10.x, msg[4]);  msg[5]  = fmaf(hs, P##_10.y, msg[5]);  \
    msg[6]  = fmaf(hs, P##_10.z, msg[6]);  msg[7]  = fmaf(hs, P##_10.w, msg[7]);  \
    msg[8]  = fmaf(hs, P##_11.x, msg[8]);  msg[9]  = fmaf(hs, P##_11.y, msg[9]);  \
    msg[10] = fmaf(hs, P##_11.z, msg[10]); msg[11] = fmaf(hs, P##_11.w, msg[11]); \
    msg[12] = fmaf(hs, P##_12.x, msg[12]); msg[13] = fmaf(hs, P##_12.y, msg[13]); \
    msg[14] = fmaf(hs, P##_12.z, msg[14]); msg[15] = fmaf(hs, P##_12.w, msg[15]); }

__global__ __launch_bounds__(256) void mp_kernel(
    const int*   __restrict__ nidx, const float* __restrict__ nd2,
    const float* __restrict__ yat,  const float* __restrict__ wpack,
    const float* __restrict__ b2,
    const float* __restrict__ gnw, const float* __restrict__ gnb,
    float* __restrict__ out)
{
    // stage all 3 layers of packed weights into LDS (uniform reads -> broadcast)
    __shared__ float4 slds[3*Q_LAY];
    {
        const float4* wg = reinterpret_cast<const float4*>(wpack);
        #pragma unroll
        for (int i = 0; i < 6; ++i) {
            const int idx = threadIdx.x + i*256;
            if (idx < 3*Q_LAY) slds[idx] = wg[idx];
        }
    }
    __syncthreads();

    const int g  = blockIdx.x * 256 + threadIdx.x;
    const int n  = g >> 3;
    const int kl = g & 7;

    const int2   iv = *reinterpret_cast<const int2*>  (nidx + n*KK + kl*2);
    const float2 dv = *reinterpret_cast<const float2*>(nd2  + n*KK + kl*2);

    float at0[DD], at1[DD];
    {
        const float4* p0 = reinterpret_cast<const float4*>(yat + (long)iv.x*DD);
        const float4* p1 = reinterpret_cast<const float4*>(yat + (long)iv.y*DD);
        const float4 a = p0[0], b = p0[1], c = p0[2], d = p0[3];
        const float4 e = p1[0], f = p1[1], h = p1[2], i = p1[3];
        at0[0]=a.x; at0[1]=a.y; at0[2]=a.z; at0[3]=a.w;
        at0[4]=b.x; at0[5]=b.y; at0[6]=b.z; at0[7]=b.w;
        at0[8]=c.x; at0[9]=c.y; at0[10]=c.z; at0[11]=c.w;
        at0[12]=d.x; at0[13]=d.y; at0[14]=d.z; at0[15]=d.w;
        at1[0]=e.x; at1[1]=e.y; at1[2]=e.z; at1[3]=e.w;
        at1[4]=f.x; at1[5]=f.y; at1[6]=f.z; at1[7]=f.w;
        at1[8]=h.x; at1[9]=h.y; at1[10]=h.z; at1[11]=h.w;
        at1[12]=i.x; at1[13]=i.y; at1[14]=i.z; at1[15]=i.w;
    }

    float pe[DD];
    #pragma unroll
    for (int h = 0; h < DD; ++h) pe[h] = 1.0f;

    for (int L = 0; L < 3; ++L) {
        const float4* wxp = slds + L*Q_LAY + Q_WX;
        const float4* wbp = slds + L*Q_LAY + Q_WB;
        const float4* wtp = slds + L*Q_LAY + Q_WT;

        float msg[DD];
        {
            const float4* bq = reinterpret_cast<const float4*>(b2 + L*DD);
            const float4 q0 = bq[0], q1 = bq[1], q2 = bq[2], q3 = bq[3];
            msg[0]=2.f*q0.x; msg[1]=2.f*q0.y; msg[2]=2.f*q0.z; msg[3]=2.f*q0.w;
            msg[4]=2.f*q1.x; msg[5]=2.f*q1.y; msg[6]=2.f*q1.z; msg[7]=2.f*q1.w;
            msg[8]=2.f*q2.x; msg[9]=2.f*q2.y; msg[10]=2.f*q2.z; msg[11]=2.f*q2.w;
            msg[12]=2.f*q3.x; msg[13]=2.f*q3.y; msg[14]=2.f*q3.z; msg[15]=2.f*q3.w;
        }

        // ping-pong software pipeline over o = 0..32 (VGPR sets, ds_read source)
        float4 pA_0,pA_1,pA_2,pA_3,pA_4,pA_5,pA_6,pA_7,pA_8,pA_9,pA_10,pA_11,pA_12;
        float4 pB_0,pB_1,pB_2,pB_3,pB_4,pB_5,pB_6,pB_7,pB_8,pB_9,pB_10,pB_11,pB_12;
        LDW(pA, 0)
        #pragma unroll 1
        for (int o = 0; o < 32; o += 2) {
            LDW(pB, o+1)     // issue o+1 ds_reads; latency hides under CMPW(pA)
            CMPW(pA)
            LDW(pA, o+2)     // o+2 <= 32 always valid
            CMPW(pB)
        }
        CMPW(pA)             // o = 32

        // sum partial msg over the 8 lanes of this point
        #pragma unroll
        for (int o = 0; o < DD; ++o) {
            msg[o] += __shfl_xor(msg[o], 1);
            msg[o] += __shfl_xor(msg[o], 2);
            msg[o] += __shfl_xor(msg[o], 4);
        }

        // GroupNorm(2,16) + leaky + residual (redundant per lane)
        const float4* gw = reinterpret_cast<const float4*>(gnw + L*DD);
        const float4* gb = reinterpret_cast<const float4*>(gnb + L*DD);
        const float4 gw0 = gw[0], gw1 = gw[1], gw2 = gw[2], gw3 = gw[3];
        const float4 gb0 = gb[0], gb1 = gb[1], gb2 = gb[2], gb3 = gb[3];
        const float gwa[DD] = { gw0.x,gw0.y,gw0.z,gw0.w, gw1.x,gw1.y,gw1.z,gw1.w,
                                gw2.x,gw2.y,gw2.z,gw2.w, gw3.x,gw3.y,gw3.z,gw3.w };
        const float gba[DD] = { gb0.x,gb0.y,gb0.z,gb0.w, gb1.x,gb1.y,gb1.z,gb1.w,
                                gb2.x,gb2.y,gb2.z,gb2.w, gb3.x,gb3.y,gb3.z,gb3.w };
        #pragma unroll
        for (int grp = 0; grp < 2; ++grp) {
            float mu = 0.0f;
            #pragma unroll
            for (int j = 0; j < 8; ++j) mu += msg[grp*8 + j];
            mu *= 0.125f;
            float var = 0.0f;
            #pragma unroll
            for (int j = 0; j < 8; ++j) { const float d = msg[grp*8 + j] - mu; var = fmaf(d, d, var); }
            var *= 0.125f;
            const float rs = rsqrtf(var + EPSGN);
            #pragma unroll
            for (int j = 0; j < 8; ++j) {
                const int c = grp*8 + j;
                const float v = (msg[c] - mu) * rs * gwa[c] + gba[c];
                pe[c] += fmaxf(v, SLOPE * v);
            }
        }
    }

    if (kl == 0) {
        float4* op = reinterpret_cast<float4*>(out + (long)n*DD);
        op[0] = make_float4(pe[0],  pe[1],  pe[2],  pe[3]);
        op[1] = make_float4(pe[4],  pe[5],  pe[6],  pe[7]);
        op[2] = make_float4(pe[8],  pe[9],  pe[10], pe[11]);
        op[3] = make_float4(pe[12], pe[13], pe[14], pe[15]);
    }
}

extern "C" void kernel_launch(void* const* d_in, const int* in_sizes, int n_in,
                              void* d_out, int out_size, void* d_ws, size_t ws_size,
                              hipStream_t stream) {
    const float* x   = (const float*)d_in[0];
    const float* y   = (const float*)d_in[1];
    const float* yat = (const float*)d_in[2];
    const int*   xb  = (const int*)  d_in[3];
    const int*   yb  = (const int*)  d_in[4];
    const float* W1  = (const float*)d_in[5];
    const float* b1  = (const float*)d_in[6];
    const float* W2  = (const float*)d_in[7];
    const float* b2  = (const float*)d_in[8];
    const float* gnw = (const float*)d_in[9];
    const float* gnb = (const float*)d_in[10];
    float* out = (float*)d_out;

    float* ypad   = (float*)((char*)d_ws + WS_PAD);
    int*   seg    = (int*)  ((char*)d_ws + WS_SEG);
    float* wpack  = (float*)((char*)d_ws + WS_WP);
    int*   ws_idx = (int*)  ((char*)d_ws + WS_IDX);
    float* ws_d2  = (float*)((char*)d_ws + WS_D2);

    repack_kernel<<<16, 256, 0, stream>>>(W1, b1, W2, y, yb, wpack, ypad, seg);
    knn_kernel<<<N_PTS/4, 256, 0, stream>>>(x, xb, ypad, seg, y, ws_idx, ws_d2);
    mp_kernel<<<(N_PTS*8)/256, 256, 0, stream>>>(
        ws_idx, ws_d2, yat, wpack, b2, gnw, gnb, out);
}

// Round 13
// 91.643 us; speedup vs baseline: 1.1187x; 1.0148x over previous
//
#include <hip/hip_runtime.h>
#include <math.h>

#define N_PTS 20000
#define M_ATM 8000
#define DD    16
#define KK    16
#define HH    33
#define BB    4
#define EPSGN 1e-5f
#define SLOPE 0.2f
#define SLOTS 36          // 36*64 = 2304 candidate slots per batch
#define PSLOT 2304
#define SENT  0xFFFFFFFFu // > any real key (real off <= 2303 < 0xFFF)

// packed layout per layer (floats): wx[33][20] | wb[33][16] | wt[33][16]
#define PK_WX   0
#define PK_WB   660
#define PK_WT   1188
#define PK_LAY  1716

// ws layout (bytes)
#define WS_PAD   0                      // 4*2304*16 = 147456 (padded f32 atom table)
#define WS_SEG   147456                 // 8 ints
#define WS_WP    147520                 // 3*1716 floats -> ends 168112
#define WS_IDX   168128                 // N*K ints
#define WS_D2    (168128 + 1280000)     // N*K floats

// ---------------- repack: weights + padded f32 atom table + batch boundaries ----
__global__ void repack_kernel(const float* __restrict__ W1, const float* __restrict__ b1,
                              const float* __restrict__ W2,
                              const float* __restrict__ y, const int* __restrict__ yb,
                              float* __restrict__ wp, float* __restrict__ ypad,
                              int* __restrict__ seg)
{
    const int tid = blockIdx.x*256 + threadIdx.x;
    const int stride = gridDim.x*256;

    for (int i = tid; i < 3*PK_LAY; i += stride) {
        const int L = i / PK_LAY, r = i % PK_LAY;
        float v;
        if (r < PK_WB) {                    // wx[o][20] = W1a(16) | b1 | w_dist | pad2
            const int o = r / 20, c = r % 20;
            if      (c < 16)  v = W1[(L*HH + o)*HH + c];
            else if (c == 16) v = b1[L*HH + o];
            else if (c == 17) v = W1[(L*HH + o)*HH + 32];
            else              v = 0.0f;
        } else if (r < PK_WT) {             // wb[o][16] = W1[o][16..31]
            const int q = r - PK_WB, o = q / 16, c = q % 16;
            v = W1[(L*HH + o)*HH + 16 + c];
        } else {                            // wt[o][16] = W2[d][o] transposed
            const int q = r - PK_WT, o = q / 16, d = q % 16;
            v = W2[(L*DD + d)*HH + o];
        }
        wp[i] = v;
    }

    // padded candidate table: [b][slot] = (-2y0,-2y1,-2y2,|y|^2), pad = +inf
    for (int p = tid; p < BB*PSLOT; p += stride) {
        const int b = p / PSLOT, o = p % PSLOT;
        int l = 0, r = M_ATM;
        while (l < r) { int m = (l+r) >> 1; if (yb[m] <  b) l = m+1; else r = m; }
        const int lo = l;
        l = 0; r = M_ATM;
        while (l < r) { int m = (l+r) >> 1; if (yb[m] <= b) l = m+1; else r = m; }
        const int hi = l;
        float4 v;
        const int j = lo + o;
        if (j < hi) {
            const double y0 = (double)y[j*3+0];
            const double y1 = (double)y[j*3+1];
            const double y2 = (double)y[j*3+2];
            v = make_float4((float)(-2.0*y0), (float)(-2.0*y1), (float)(-2.0*y2),
                            (float)(y0*y0 + y1*y1 + y2*y2));
        } else {
            v = make_float4(0.0f, 0.0f, 0.0f, __builtin_inff());
        }
        reinterpret_cast<float4*>(ypad)[p] = v;
    }

    for (int j = tid; j < M_ATM; j += stride) {
        const int bcur  = yb[j];
        const int bprev = (j == 0) ? -1 : yb[j-1];
        for (int t = bprev+1; t <= bcur; ++t) seg[t] = j;
        if (j == M_ATM-1) { for (int t = bcur+1; t <= BB; ++t) seg[t] = M_ATM; }
    }
}

__device__ __forceinline__ unsigned wave_min_u32(unsigned v) {
    #define SW(OFF) { const unsigned o = (unsigned)__builtin_amdgcn_ds_swizzle((int)v, OFF); v = (o < v) ? o : v; }
    SW(0x041F) SW(0x081F) SW(0x101F) SW(0x201F) SW(0x401F)
    #undef SW
    { const unsigned o = (unsigned)__shfl_xor((int)v, 32); v = (o < v) ? o : v; }
    return v;
}

// ---------------- KNN: one WAVE per point, u32 truncated-key selection ----------
__global__ __launch_bounds__(256) void knn_kernel(
    const float* __restrict__ x, const int* __restrict__ xb,
    const float* __restrict__ ypad, const int* __restrict__ seg,
    const float* __restrict__ yg,
    int* __restrict__ out_idx, float* __restrict__ out_d2)
{
    const int wv   = threadIdx.x >> 6;
    const int lane = threadIdx.x & 63;
    const int n    = blockIdx.x * 4 + wv;

    const float xf0 = x[n*3+0], xf1 = x[n*3+1], xf2 = x[n*3+2];
    const float sxf = fmaf(xf0, xf0, fmaf(xf1, xf1, xf2*xf2));
    const int b  = xb[n];
    const int lo = seg[b];
    const float4* __restrict__ base =
        reinterpret_cast<const float4*>(ypad) + b*PSLOT + lane;

    // per-lane sorted top-4 keys via unconditional min/max network
    unsigned m0 = SENT, m1 = SENT, m2 = SENT, m3 = SENT;
    #pragma unroll
    for (int s = 0; s < SLOTS; ++s) {
        const float4 q = base[64*s];
        float dd = fmaf(xf2, q.z, fmaf(xf1, q.y, fmaf(xf0, q.x, sxf + q.w)));
        dd = fmaxf(dd, 0.0f);
        const unsigned kb = (__float_as_uint(dd) & 0xFFFFF000u)
                          | (unsigned)(lane | (s << 6));
        const unsigned a0 = min(m0, kb), c0 = max(m0, kb);
        const unsigned a1 = min(m1, c0), c1 = max(m1, c0);
        const unsigned a2 = min(m2, c1), c2 = max(m2, c1);
        const unsigned a3 = min(m3, c2);
        m0 = a0; m1 = a1; m2 = a2; m3 = a3;
    }

    unsigned long long cmask = 0ull;   // consumed slots (for rare rebuild)
    unsigned res_key = 0, h16 = 0;

    #define POPWIN(H)                                                         \
        if (lane == ((H) & 63u)) {                                            \
            cmask |= 1ull << (((H) >> 6) & 63u);                              \
            m0 = m1; m1 = m2; m2 = m3; m3 = SENT;                             \
            if (m0 == SENT) {                                                 \
                _Pragma("unroll 1")                                           \
                for (int s2 = 0; s2 < SLOTS; ++s2) {                          \
                    const float4 q2 = base[64*s2];                            \
                    float d2f = fmaf(xf2, q2.z, fmaf(xf1, q2.y,               \
                                 fmaf(xf0, q2.x, sxf + q2.w)));               \
                    d2f = fmaxf(d2f, 0.0f);                                   \
                    unsigned kb2 = (__float_as_uint(d2f) & 0xFFFFF000u)       \
                                 | (unsigned)(lane | (s2 << 6));              \
                    if ((cmask >> s2) & 1ull) kb2 = SENT;                     \
                    const unsigned a0 = min(m0, kb2), c0 = max(m0, kb2);      \
                    const unsigned a1 = min(m1, c0), c1 = max(m1, c0);        \
                    const unsigned a2 = min(m2, c1), c2 = max(m2, c1);        \
                    const unsigned a3 = min(m3, c2);                          \
                    m0 = a0; m1 = a1; m2 = a2; m3 = a3;                       \
                }                                                             \
            }                                                                 \
        }

    for (int r = 0; r < KK; ++r) {
        const unsigned h = wave_min_u32(m0);   // wave-uniform winner key
        if (lane == r) res_key = h;
        h16 = h;
        POPWIN(h)
    }

    // margin extras: truncation (2^-11 rel) + f32 eval error coverage
    int e = 0;
    {
        const float d16t = __uint_as_float(h16 & 0xFFFFF000u);
        const unsigned limbits = __float_as_uint(fmaf(d16t, 1.0025f, 0.01f));
        while (e < 8) {
            const unsigned h = wave_min_u32(m0);
            if ((h & 0xFFFFF000u) > limbits) break;
            if (lane == KK + e) res_key = h;
            POPWIN(h)
            ++e;
        }
    }
    #undef POPWIN

    // finalize: exact f64 distances for the 16+e survivors
    const int nact = KK + e;
    const bool have = (lane < nact);
    const unsigned off = res_key & 0xFFFu;
    double dd64 = 0.0;
    if (have) {
        const int j = lo + (int)off;
        const double yy0 = (double)yg[j*3+0];
        const double yy1 = (double)yg[j*3+1];
        const double yy2 = (double)yg[j*3+2];
        const double xd0 = (double)xf0, xd1 = (double)xf1, xd2 = (double)xf2;
        const double sxd = fma(xd0, xd0, fma(xd1, xd1, xd2*xd2));
        const double syd = fma(yy0, yy0, fma(yy1, yy1, yy2*yy2));
        dd64 = fma(xd2, -2.0*yy2, fma(xd1, -2.0*yy1, fma(xd0, -2.0*yy0, sxd + syd)));
        dd64 = fmax(dd64, 0.0);
    }

    if (e == 0) {
        if (have) {
            out_idx[n*KK + lane] = lo + (int)off;
            out_d2 [n*KK + lane] = (float)dd64;
        }
    } else {
        const unsigned long long fkey = have
            ? (((unsigned long long)__double_as_longlong(dd64) & ~0xFFFull) | off)
            : 0xFFFFFFFFFFFFFFFFull;
        int rank = 0;
        #pragma unroll 1
        for (int t = 0; t < nact; ++t) {
            const unsigned klo = (unsigned)__builtin_amdgcn_readlane((int)(unsigned)fkey, t);
            const unsigned khi = (unsigned)__builtin_amdgcn_readlane((int)(unsigned)(fkey >> 32), t);
            const unsigned long long kt = ((unsigned long long)khi << 32) | klo;
            rank += (kt < fkey) ? 1 : 0;
        }
        if (have && rank < KK) {
            out_idx[n*KK + rank] = lo + (int)off;
            out_d2 [n*KK + rank] = (float)dd64;
        }
    }
}

// ---------------- MP: 16 lanes/point, 1 k/lane, rolled o-loop (s_load weights) ----
#define DOT16(res, A, q0, q1, q2, q3) {                                 \
    float _e = res, _o = 0.0f;                                          \
    _e = fmaf(A[0],  q0.x, _e); _o = fmaf(A[1],  q0.y, _o);             \
    _e = fmaf(A[2],  q0.z, _e); _o = fmaf(A[3],  q0.w, _o);             \
    _e = fmaf(A[4],  q1.x, _e); _o = fmaf(A[5],  q1.y, _o);             \
    _e = fmaf(A[6],  q1.z, _e); _o = fmaf(A[7],  q1.w, _o);             \
    _e = fmaf(A[8],  q2.x, _e); _o = fmaf(A[9],  q2.y, _o);             \
    _e = fmaf(A[10], q2.z, _e); _o = fmaf(A[11], q2.w, _o);             \
    _e = fmaf(A[12], q3.x, _e); _o = fmaf(A[13], q3.y, _o);             \
    _e = fmaf(A[14], q3.z, _e); _o = fmaf(A[15], q3.w, _o);             \
    res = _e + _o; }

__global__ __launch_bounds__(256) void mp_kernel(
    const int*   __restrict__ nidx, const float* __restrict__ nd2,
    const float* __restrict__ yat,  const float* __restrict__ wpack,
    const float* __restrict__ b2,
    const float* __restrict__ gnw, const float* __restrict__ gnb,
    float* __restrict__ out)
{
    const int g  = blockIdx.x * 256 + threadIdx.x;
    const int n  = g >> 4;
    const int kl = g & 15;

    const int   idx  = nidx[n*KK + kl];
    const float dist = nd2 [n*KK + kl];

    float at[DD];
    {
        const float4* p0 = reinterpret_cast<const float4*>(yat + (long)idx*DD);
        const float4 a = p0[0], b = p0[1], c = p0[2], d = p0[3];
        at[0]=a.x;  at[1]=a.y;  at[2]=a.z;  at[3]=a.w;
        at[4]=b.x;  at[5]=b.y;  at[6]=b.z;  at[7]=b.w;
        at[8]=c.x;  at[9]=c.y;  at[10]=c.z; at[11]=c.w;
        at[12]=d.x; at[13]=d.y; at[14]=d.z; at[15]=d.w;
    }

    float pe[DD];
    #pragma unroll
    for (int h = 0; h < DD; ++h) pe[h] = 1.0f;

    for (int L = 0; L < 3; ++L) {
        const float4* wxp = reinterpret_cast<const float4*>(wpack + L*PK_LAY + PK_WX);
        const float4* wbp = reinterpret_cast<const float4*>(wpack + L*PK_LAY + PK_WB);
        const float4* wtp = reinterpret_cast<const float4*>(wpack + L*PK_LAY + PK_WT);

        float msg[DD];
        {
            const float4* bq = reinterpret_cast<const float4*>(b2 + L*DD);
            const float4 q0 = bq[0], q1 = bq[1], q2 = bq[2], q3 = bq[3];
            msg[0]=q0.x;  msg[1]=q0.y;  msg[2]=q0.z;  msg[3]=q0.w;
            msg[4]=q1.x;  msg[5]=q1.y;  msg[6]=q1.z;  msg[7]=q1.w;
            msg[8]=q2.x;  msg[9]=q2.y;  msg[10]=q2.z; msg[11]=q2.w;
            msg[12]=q3.x; msg[13]=q3.y; msg[14]=q3.z; msg[15]=q3.w;
        }

        #pragma unroll 1
        for (int o = 0; o < HH; ++o) {
            const float4 x0 = wxp[o*5+0], x1 = wxp[o*5+1], x2 = wxp[o*5+2],
                         x3 = wxp[o*5+3], x4 = wxp[o*5+4];
            const float4 y0 = wbp[o*4+0], y1 = wbp[o*4+1], y2 = wbp[o*4+2],
                         y3 = wbp[o*4+3];
            const float4 t0 = wtp[o*4+0], t1 = wtp[o*4+1], t2 = wtp[o*4+2],
                         t3 = wtp[o*4+3];

            float bas = x4.x;                 // b1[o]
            DOT16(bas, pe, x0, x1, x2, x3);   // + pe . W1a[o]
            float u = fmaf(dist, x4.y, bas);  // + dist*W1[o][32]
            DOT16(u, at, y0, y1, y2, y3);     // + at . W1b[o]
            const float hs = fmaxf(u, SLOPE*u);  // leaky_relu

            msg[0]  = fmaf(hs, t0.x, msg[0]);  msg[1]  = fmaf(hs, t0.y, msg[1]);
            msg[2]  = fmaf(hs, t0.z, msg[2]);  msg[3]  = fmaf(hs, t0.w, msg[3]);
            msg[4]  = fmaf(hs, t1.x, msg[4]);  msg[5]  = fmaf(hs, t1.y, msg[5]);
            msg[6]  = fmaf(hs, t1.z, msg[6]);  msg[7]  = fmaf(hs, t1.w, msg[7]);
            msg[8]  = fmaf(hs, t2.x, msg[8]);  msg[9]  = fmaf(hs, t2.y, msg[9]);
            msg[10] = fmaf(hs, t2.z, msg[10]); msg[11] = fmaf(hs, t2.w, msg[11]);
            msg[12] = fmaf(hs, t3.x, msg[12]); msg[13] = fmaf(hs, t3.y, msg[13]);
            msg[14] = fmaf(hs, t3.z, msg[14]); msg[15] = fmaf(hs, t3.w, msg[15]);
        }

        // sum partial msg over the 16 lanes of this point
        #pragma unroll
        for (int o = 0; o < DD; ++o) {
            msg[o] += __shfl_xor(msg[o], 1);
            msg[o] += __shfl_xor(msg[o], 2);
            msg[o] += __shfl_xor(msg[o], 4);
            msg[o] += __shfl_xor(msg[o], 8);
        }

        // GroupNorm(2,16) + leaky + residual (redundant per lane)
        const float4* gw = reinterpret_cast<const float4*>(gnw + L*DD);
        const float4* gb = reinterpret_cast<const float4*>(gnb + L*DD);
        const float4 gw0 = gw[0], gw1 = gw[1], gw2 = gw[2], gw3 = gw[3];
        const float4 gb0 = gb[0], gb1 = gb[1], gb2 = gb[2], gb3 = gb[3];
        const float gwa[DD] = { gw0.x,gw0.y,gw0.z,gw0.w, gw1.x,gw1.y,gw1.z,gw1.w,
                                gw2.x,gw2.y,gw2.z,gw2.w, gw3.x,gw3.y,gw3.z,gw3.w };
        const float gba[DD] = { gb0.x,gb0.y,gb0.z,gb0.w, gb1.x,gb1.y,gb1.z,gb1.w,
                                gb2.x,gb2.y,gb2.z,gb2.w, gb3.x,gb3.y,gb3.z,gb3.w };
        #pragma unroll
        for (int grp = 0; grp < 2; ++grp) {
            float mu = 0.0f;
            #pragma unroll
            for (int j = 0; j < 8; ++j) mu += msg[grp*8 + j];
            mu *= 0.125f;
            float var = 0.0f;
            #pragma unroll
            for (int j = 0; j < 8; ++j) { const float d = msg[grp*8 + j] - mu; var = fmaf(d, d, var); }
            var *= 0.125f;
            const float rs = rsqrtf(var + EPSGN);
            #pragma unroll
            for (int j = 0; j < 8; ++j) {
                const int c = grp*8 + j;
                const float v = (msg[c] - mu) * rs * gwa[c] + gba[c];
                pe[c] += fmaxf(v, SLOPE * v);
            }
        }
    }

    if (kl == 0) {
        float4* op = reinterpret_cast<float4*>(out + (long)n*DD);
        op[0] = make_float4(pe[0],  pe[1],  pe[2],  pe[3]);
        op[1] = make_float4(pe[4],  pe[5],  pe[6],  pe[7]);
        op[2] = make_float4(pe[8],  pe[9],  pe[10], pe[11]);
        op[3] = make_float4(pe[12], pe[13], pe[14], pe[15]);
    }
}

extern "C" void kernel_launch(void* const* d_in, const int* in_sizes, int n_in,
                              void* d_out, int out_size, void* d_ws, size_t ws_size,
                              hipStream_t stream) {
    const float* x   = (const float*)d_in[0];
    const float* y   = (const float*)d_in[1];
    const float* yat = (const float*)d_in[2];
    const int*   xb  = (const int*)  d_in[3];
    const int*   yb  = (const int*)  d_in[4];
    const float* W1  = (const float*)d_in[5];
    const float* b1  = (const float*)d_in[6];
    const float* W2  = (const float*)d_in[7];
    const float* b2  = (const float*)d_in[8];
    const float* gnw = (const float*)d_in[9];
    const float* gnb = (const float*)d_in[10];
    float* out = (float*)d_out;

    float* ypad   = (float*)((char*)d_ws + WS_PAD);
    int*   seg    = (int*)  ((char*)d_ws + WS_SEG);
    float* wpack  = (float*)((char*)d_ws + WS_WP);
    int*   ws_idx = (int*)  ((char*)d_ws + WS_IDX);
    float* ws_d2  = (float*)((char*)d_ws + WS_D2);

    repack_kernel<<<16, 256, 0, stream>>>(W1, b1, W2, y, yb, wpack, ypad, seg);
    knn_kernel<<<N_PTS/4, 256, 0, stream>>>(x, xb, ypad, seg, y, ws_idx, ws_d2);
    mp_kernel<<<(N_PTS*16)/256, 256, 0, stream>>>(
        ws_idx, ws_d2, yat, wpack, b2, gnw, gnb, out);
}

// Round 14
// 88.959 us; speedup vs baseline: 1.1524x; 1.0302x over previous
//
#include <hip/hip_runtime.h>
#include <math.h>

#define N_PTS 20000
#define M_ATM 8000
#define DD    16
#define KK    16
#define HH    33
#define BB    4
#define EPSGN 1e-5f
#define SLOPE 0.2f
#define SLOTS 36          // 36*64 = 2304 candidate slots per batch
#define PSLOT 2304
#define SENT  0xFFFFFFFFu // > any real key (real off <= 2303 < 0xFFF)

// packed layout per layer (floats): wx[33][20] | wb[33][16] | wt[33][16]
#define PK_WX   0
#define PK_WB   660
#define PK_WT   1188
#define PK_LAY  1716

// ws layout (bytes)
#define WS_PAD   0                      // 4*2304*16 = 147456 (padded f32 atom table)
#define WS_SEG   147456                 // 8 ints
#define WS_WP    147520                 // 3*1716 floats -> ends 168112
#define WS_IDX   168128                 // N*K ints
#define WS_D2    (168128 + 1280000)     // N*K floats

// ---------------- repack: weights + padded f32 atom table + batch boundaries ----
__global__ void repack_kernel(const float* __restrict__ W1, const float* __restrict__ b1,
                              const float* __restrict__ W2,
                              const float* __restrict__ y, const int* __restrict__ yb,
                              float* __restrict__ wp, float* __restrict__ ypad,
                              int* __restrict__ seg)
{
    const int tid = blockIdx.x*256 + threadIdx.x;
    const int stride = gridDim.x*256;

    for (int i = tid; i < 3*PK_LAY; i += stride) {
        const int L = i / PK_LAY, r = i % PK_LAY;
        float v;
        if (r < PK_WB) {                    // wx[o][20] = W1a(16) | b1 | w_dist | pad2
            const int o = r / 20, c = r % 20;
            if      (c < 16)  v = W1[(L*HH + o)*HH + c];
            else if (c == 16) v = b1[L*HH + o];
            else if (c == 17) v = W1[(L*HH + o)*HH + 32];
            else              v = 0.0f;
        } else if (r < PK_WT) {             // wb[o][16] = W1[o][16..31]
            const int q = r - PK_WB, o = q / 16, c = q % 16;
            v = W1[(L*HH + o)*HH + 16 + c];
        } else {                            // wt[o][16] = W2[d][o] transposed
            const int q = r - PK_WT, o = q / 16, d = q % 16;
            v = W2[(L*DD + d)*HH + o];
        }
        wp[i] = v;
    }

    // padded candidate table: [b][slot] = (-2y0,-2y1,-2y2,|y|^2), pad = +inf
    for (int p = tid; p < BB*PSLOT; p += stride) {
        const int b = p / PSLOT, o = p % PSLOT;
        int l = 0, r = M_ATM;
        while (l < r) { int m = (l+r) >> 1; if (yb[m] <  b) l = m+1; else r = m; }
        const int lo = l;
        l = 0; r = M_ATM;
        while (l < r) { int m = (l+r) >> 1; if (yb[m] <= b) l = m+1; else r = m; }
        const int hi = l;
        float4 v;
        const int j = lo + o;
        if (j < hi) {
            const double y0 = (double)y[j*3+0];
            const double y1 = (double)y[j*3+1];
            const double y2 = (double)y[j*3+2];
            v = make_float4((float)(-2.0*y0), (float)(-2.0*y1), (float)(-2.0*y2),
                            (float)(y0*y0 + y1*y1 + y2*y2));
        } else {
            v = make_float4(0.0f, 0.0f, 0.0f, __builtin_inff());
        }
        reinterpret_cast<float4*>(ypad)[p] = v;
    }

    for (int j = tid; j < M_ATM; j += stride) {
        const int bcur  = yb[j];
        const int bprev = (j == 0) ? -1 : yb[j-1];
        for (int t = bprev+1; t <= bcur; ++t) seg[t] = j;
        if (j == M_ATM-1) { for (int t = bcur+1; t <= BB; ++t) seg[t] = M_ATM; }
    }
}

__device__ __forceinline__ unsigned wave_min_u32(unsigned v) {
    #define SW(OFF) { const unsigned o = (unsigned)__builtin_amdgcn_ds_swizzle((int)v, OFF); v = (o < v) ? o : v; }
    SW(0x041F) SW(0x081F) SW(0x101F) SW(0x201F) SW(0x401F)
    #undef SW
    { const unsigned o = (unsigned)__shfl_xor((int)v, 32); v = (o < v) ? o : v; }
    return v;
}

// ---------------- KNN: one WAVE per point, u32 truncated-key selection ----------
__global__ __launch_bounds__(256) void knn_kernel(
    const float* __restrict__ x, const int* __restrict__ xb,
    const float* __restrict__ ypad, const int* __restrict__ seg,
    const float* __restrict__ yg,
    int* __restrict__ out_idx, float* __restrict__ out_d2)
{
    const int wv   = threadIdx.x >> 6;
    const int lane = threadIdx.x & 63;
    const int n    = blockIdx.x * 4 + wv;

    const float xf0 = x[n*3+0], xf1 = x[n*3+1], xf2 = x[n*3+2];
    const float sxf = fmaf(xf0, xf0, fmaf(xf1, xf1, xf2*xf2));
    const int b  = xb[n];
    const int lo = seg[b];
    const float4* __restrict__ base =
        reinterpret_cast<const float4*>(ypad) + b*PSLOT + lane;

    // per-lane sorted top-4 keys via unconditional min/max network
    unsigned m0 = SENT, m1 = SENT, m2 = SENT, m3 = SENT;
    #pragma unroll
    for (int s = 0; s < SLOTS; ++s) {
        const float4 q = base[64*s];
        float dd = fmaf(xf2, q.z, fmaf(xf1, q.y, fmaf(xf0, q.x, sxf + q.w)));
        dd = fmaxf(dd, 0.0f);
        const unsigned kb = (__float_as_uint(dd) & 0xFFFFF000u)
                          | (unsigned)(lane | (s << 6));
        const unsigned a0 = min(m0, kb), c0 = max(m0, kb);
        const unsigned a1 = min(m1, c0), c1 = max(m1, c0);
        const unsigned a2 = min(m2, c1), c2 = max(m2, c1);
        const unsigned a3 = min(m3, c2);
        m0 = a0; m1 = a1; m2 = a2; m3 = a3;
    }

    unsigned long long cmask = 0ull;   // consumed slots (for rare rebuild)
    unsigned res_key = 0, h16 = 0;

    #define POPWIN(H)                                                         \
        if (lane == ((H) & 63u)) {                                            \
            cmask |= 1ull << (((H) >> 6) & 63u);                              \
            m0 = m1; m1 = m2; m2 = m3; m3 = SENT;                             \
            if (m0 == SENT) {                                                 \
                _Pragma("unroll 1")                                           \
                for (int s2 = 0; s2 < SLOTS; ++s2) {                          \
                    const float4 q2 = base[64*s2];                            \
                    float d2f = fmaf(xf2, q2.z, fmaf(xf1, q2.y,               \
                                 fmaf(xf0, q2.x, sxf + q2.w)));               \
                    d2f = fmaxf(d2f, 0.0f);                                   \
                    unsigned kb2 = (__float_as_uint(d2f) & 0xFFFFF000u)       \
                                 | (unsigned)(lane | (s2 << 6));              \
                    if ((cmask >> s2) & 1ull) kb2 = SENT;                     \
                    const unsigned a0 = min(m0, kb2), c0 = max(m0, kb2);      \
                    const unsigned a1 = min(m1, c0), c1 = max(m1, c0);        \
                    const unsigned a2 = min(m2, c1), c2 = max(m2, c1);        \
                    const unsigned a3 = min(m3, c2);                          \
                    m0 = a0; m1 = a1; m2 = a2; m3 = a3;                       \
                }                                                             \
            }                                                                 \
        }

    for (int r = 0; r < KK; ++r) {
        const unsigned h = wave_min_u32(m0);   // wave-uniform winner key
        if (lane == r) res_key = h;
        h16 = h;
        POPWIN(h)
    }

    // margin extras: truncation (2^-11 rel) + f32 eval error coverage
    int e = 0;
    {
        const float d16t = __uint_as_float(h16 & 0xFFFFF000u);
        const unsigned limbits = __float_as_uint(fmaf(d16t, 1.0025f, 0.01f));
        while (e < 8) {
            const unsigned h = wave_min_u32(m0);
            if ((h & 0xFFFFF000u) > limbits) break;
            if (lane == KK + e) res_key = h;
            POPWIN(h)
            ++e;
        }
    }
    #undef POPWIN

    // finalize: exact f64 distances for the 16+e survivors
    const int nact = KK + e;
    const bool have = (lane < nact);
    const unsigned off = res_key & 0xFFFu;
    double dd64 = 0.0;
    if (have) {
        const int j = lo + (int)off;
        const double yy0 = (double)yg[j*3+0];
        const double yy1 = (double)yg[j*3+1];
        const double yy2 = (double)yg[j*3+2];
        const double xd0 = (double)xf0, xd1 = (double)xf1, xd2 = (double)xf2;
        const double sxd = fma(xd0, xd0, fma(xd1, xd1, xd2*xd2));
        const double syd = fma(yy0, yy0, fma(yy1, yy1, yy2*yy2));
        dd64 = fma(xd2, -2.0*yy2, fma(xd1, -2.0*yy1, fma(xd0, -2.0*yy0, sxd + syd)));
        dd64 = fmax(dd64, 0.0);
    }

    if (e == 0) {
        if (have) {
            out_idx[n*KK + lane] = lo + (int)off;
            out_d2 [n*KK + lane] = (float)dd64;
        }
    } else {
        const unsigned long long fkey = have
            ? (((unsigned long long)__double_as_longlong(dd64) & ~0xFFFull) | off)
            : 0xFFFFFFFFFFFFFFFFull;
        int rank = 0;
        #pragma unroll 1
        for (int t = 0; t < nact; ++t) {
            const unsigned klo = (unsigned)__builtin_amdgcn_readlane((int)(unsigned)fkey, t);
            const unsigned khi = (unsigned)__builtin_amdgcn_readlane((int)(unsigned)(fkey >> 32), t);
            const unsigned long long kt = ((unsigned long long)khi << 32) | klo;
            rank += (kt < fkey) ? 1 : 0;
        }
        if (have && rank < KK) {
            out_idx[n*KK + rank] = lo + (int)off;
            out_d2 [n*KK + rank] = (float)dd64;
        }
    }
}

// ---------------- MP: 16 lanes/point, cooperative base + hsum-first W2 ----------
#define DOT16(res, A, q0, q1, q2, q3) {                                 \
    float _e = res, _o = 0.0f;                                          \
    _e = fmaf(A[0],  q0.x, _e); _o = fmaf(A[1],  q0.y, _o);             \
    _e = fmaf(A[2],  q0.z, _e); _o = fmaf(A[3],  q0.w, _o);             \
    _e = fmaf(A[4],  q1.x, _e); _o = fmaf(A[5],  q1.y, _o);             \
    _e = fmaf(A[6],  q1.z, _e); _o = fmaf(A[7],  q1.w, _o);             \
    _e = fmaf(A[8],  q2.x, _e); _o = fmaf(A[9],  q2.y, _o);             \
    _e = fmaf(A[10], q2.z, _e); _o = fmaf(A[11], q2.w, _o);             \
    _e = fmaf(A[12], q3.x, _e); _o = fmaf(A[13], q3.y, _o);             \
    _e = fmaf(A[14], q3.z, _e); _o = fmaf(A[15], q3.w, _o);             \
    res = _e + _o; }

__global__ __launch_bounds__(256) void mp_kernel(
    const int*   __restrict__ nidx, const float* __restrict__ nd2,
    const float* __restrict__ yat,  const float* __restrict__ wpack,
    const float* __restrict__ b2,
    const float* __restrict__ gnw, const float* __restrict__ gnb,
    float* __restrict__ out)
{
    const int g  = blockIdx.x * 256 + threadIdx.x;
    const int n  = g >> 4;
    const int kl = g & 15;     // lane's k AND lane's output channel

    const int   idx  = nidx[n*KK + kl];
    const float dist = nd2 [n*KK + kl];

    float at[DD];
    {
        const float4* p0 = reinterpret_cast<const float4*>(yat + (long)idx*DD);
        const float4 a = p0[0], b = p0[1], c = p0[2], d = p0[3];
        at[0]=a.x;  at[1]=a.y;  at[2]=a.z;  at[3]=a.w;
        at[4]=b.x;  at[5]=b.y;  at[6]=b.z;  at[7]=b.w;
        at[8]=c.x;  at[9]=c.y;  at[10]=c.z; at[11]=c.w;
        at[12]=d.x; at[13]=d.y; at[14]=d.z; at[15]=d.w;
    }

    float pe[DD];
    #pragma unroll
    for (int h = 0; h < DD; ++h) pe[h] = 1.0f;
    float pe_own = 1.0f;

    for (int L = 0; L < 3; ++L) {
        const float* wx = wpack + L*PK_LAY + PK_WX;   // [o][20]
        const float* wb = wpack + L*PK_LAY + PK_WB;   // [o][16] (uniform use)
        const float* wt = wpack + L*PK_LAY + PK_WT;   // [o][16] (col kl per lane)

        // W2 column for own channel: w2r[o] = W2[kl][o]  (coalesced dword loads)
        float w2r[HH];
        #pragma unroll
        for (int o = 0; o < HH; ++o) w2r[o] = wt[o*16 + kl];

        // cooperative base: lane owns rows kl and kl+16; row 32 uniform
        float baseA, baseB, base32;
        {
            const float4* ra = reinterpret_cast<const float4*>(wx + kl*20);
            const float4 a0 = ra[0], a1 = ra[1], a2 = ra[2], a3 = ra[3], a4 = ra[4];
            float t = a4.x; DOT16(t, pe, a0, a1, a2, a3); baseA = t;
            const float4* rb = reinterpret_cast<const float4*>(wx + (kl+16)*20);
            const float4 b0 = rb[0], b1_ = rb[1], b2_ = rb[2], b3 = rb[3], b4 = rb[4];
            t = b4.x; DOT16(t, pe, b0, b1_, b2_, b3); baseB = t;
            const float4* rc = reinterpret_cast<const float4*>(wx + 32*20);
            const float4 c0 = rc[0], c1 = rc[1], c2 = rc[2], c3 = rc[3], c4 = rc[4];
            t = c4.x; DOT16(t, pe, c0, c1, c2, c3); base32 = t;
        }

        float msg_d = 16.0f * b2[L*DD + kl];

        #pragma unroll
        for (int o = 0; o < HH; ++o) {
            float bo;
            if      (o < 16) bo = __shfl(baseA, o,      16);
            else if (o < 32) bo = __shfl(baseB, o - 16, 16);
            else             bo = base32;
            const float wd = wx[o*20 + 17];                       // uniform
            const float4* wr = reinterpret_cast<const float4*>(wb + o*16);
            const float4 y0 = wr[0], y1 = wr[1], y2 = wr[2], y3 = wr[3];
            float u = fmaf(dist, wd, bo);
            DOT16(u, at, y0, y1, y2, y3);
            float hs = fmaxf(u, SLOPE*u);          // leaky per-k
            hs += __shfl_xor(hs, 1, 16);           // sum over the point's 16 k's
            hs += __shfl_xor(hs, 2, 16);
            hs += __shfl_xor(hs, 4, 16);
            hs += __shfl_xor(hs, 8, 16);
            msg_d = fmaf(hs, w2r[o], msg_d);       // own channel only
        }

        // GroupNorm(2,16): lane owns channel kl; group = kl>>3 (8 lanes)
        float s = msg_d;
        s += __shfl_xor(s, 1, 16); s += __shfl_xor(s, 2, 16); s += __shfl_xor(s, 4, 16);
        const float mu = s * 0.125f;
        const float dvn = msg_d - mu;
        float v2 = dvn * dvn;
        v2 += __shfl_xor(v2, 1, 16); v2 += __shfl_xor(v2, 2, 16); v2 += __shfl_xor(v2, 4, 16);
        const float rs = rsqrtf(v2 * 0.125f + EPSGN);
        const float v = dvn * rs * gnw[L*DD + kl] + gnb[L*DD + kl];
        pe_own += fmaxf(v, SLOPE * v);

        // rebuild replicated pe[16] for next layer's base phase
        #pragma unroll
        for (int j = 0; j < DD; ++j) pe[j] = __shfl(pe_own, j, 16);
    }

    if (kl == 0) {
        float4* op = reinterpret_cast<float4*>(out + (long)n*DD);
        op[0] = make_float4(pe[0],  pe[1],  pe[2],  pe[3]);
        op[1] = make_float4(pe[4],  pe[5],  pe[6],  pe[7]);
        op[2] = make_float4(pe[8],  pe[9],  pe[10], pe[11]);
        op[3] = make_float4(pe[12], pe[13], pe[14], pe[15]);
    }
}

extern "C" void kernel_launch(void* const* d_in, const int* in_sizes, int n_in,
                              void* d_out, int out_size, void* d_ws, size_t ws_size,
                              hipStream_t stream) {
    const float* x   = (const float*)d_in[0];
    const float* y   = (const float*)d_in[1];
    const float* yat = (const float*)d_in[2];
    const int*   xb  = (const int*)  d_in[3];
    const int*   yb  = (const int*)  d_in[4];
    const float* W1  = (const float*)d_in[5];
    const float* b1  = (const float*)d_in[6];
    const float* W2  = (const float*)d_in[7];
    const float* b2  = (const float*)d_in[8];
    const float* gnw = (const float*)d_in[9];
    const float* gnb = (const float*)d_in[10];
    float* out = (float*)d_out;

    float* ypad   = (float*)((char*)d_ws + WS_PAD);
    int*   seg    = (int*)  ((char*)d_ws + WS_SEG);
    float* wpack  = (float*)((char*)d_ws + WS_WP);
    int*   ws_idx = (int*)  ((char*)d_ws + WS_IDX);
    float* ws_d2  = (float*)((char*)d_ws + WS_D2);

    repack_kernel<<<16, 256, 0, stream>>>(W1, b1, W2, y, yb, wpack, ypad, seg);
    knn_kernel<<<N_PTS/4, 256, 0, stream>>>(x, xb, ypad, seg, y, ws_idx, ws_d2);
    mp_kernel<<<(N_PTS*16)/256, 256, 0, stream>>>(
        ws_idx, ws_d2, yat, wpack, b2, gnw, gnb, out);
}

// Round 15
// 88.957 us; speedup vs baseline: 1.1525x; 1.0000x over previous
//
#include <hip/hip_runtime.h>
#include <math.h>

#define N_PTS 20000
#define M_ATM 8000
#define DD    16
#define KK    16
#define HH    33
#define BB    4
#define EPSGN 1e-5f
#define SLOPE 0.2f
#define SLOTS 36          // 36*64 = 2304 candidate slots per batch
#define PSLOT 2304
#define SENT  0xFFFFFFFFu // > any real key (real off <= 2303 < 0xFFF)

// packed layout per layer (floats): wx[33][20] | wb[33][16] | wt[33][16]
#define PK_WX   0
#define PK_WB   660
#define PK_WT   1188
#define PK_LAY  1716

// ws layout (bytes)
#define WS_PAD   0                      // 4*2304*16 = 147456 (padded f32 atom table)
#define WS_SEG   147456                 // 8 ints
#define WS_WP    147520                 // 3*1716 floats -> ends 168112
#define WS_IDX   168128                 // N*K ints
#define WS_D2    (168128 + 1280000)     // N*K floats

// ---------------- repack: weights + padded f32 atom table + batch boundaries ----
__global__ void repack_kernel(const float* __restrict__ W1, const float* __restrict__ b1,
                              const float* __restrict__ W2,
                              const float* __restrict__ y, const int* __restrict__ yb,
                              float* __restrict__ wp, float* __restrict__ ypad,
                              int* __restrict__ seg)
{
    const int tid = blockIdx.x*256 + threadIdx.x;
    const int stride = gridDim.x*256;

    for (int i = tid; i < 3*PK_LAY; i += stride) {
        const int L = i / PK_LAY, r = i % PK_LAY;
        float v;
        if (r < PK_WB) {                    // wx[o][20] = W1a(16) | b1 | w_dist | pad2
            const int o = r / 20, c = r % 20;
            if      (c < 16)  v = W1[(L*HH + o)*HH + c];
            else if (c == 16) v = b1[L*HH + o];
            else if (c == 17) v = W1[(L*HH + o)*HH + 32];
            else              v = 0.0f;
        } else if (r < PK_WT) {             // wb[o][16] = W1[o][16..31]
            const int q = r - PK_WB, o = q / 16, c = q % 16;
            v = W1[(L*HH + o)*HH + 16 + c];
        } else {                            // wt[o][16] = W2[d][o] transposed
            const int q = r - PK_WT, o = q / 16, d = q % 16;
            v = W2[(L*DD + d)*HH + o];
        }
        wp[i] = v;
    }

    // padded candidate table: [b][slot] = (-2y0,-2y1,-2y2,|y|^2), pad = +inf
    for (int p = tid; p < BB*PSLOT; p += stride) {
        const int b = p / PSLOT, o = p % PSLOT;
        int l = 0, r = M_ATM;
        while (l < r) { int m = (l+r) >> 1; if (yb[m] <  b) l = m+1; else r = m; }
        const int lo = l;
        l = 0; r = M_ATM;
        while (l < r) { int m = (l+r) >> 1; if (yb[m] <= b) l = m+1; else r = m; }
        const int hi = l;
        float4 v;
        const int j = lo + o;
        if (j < hi) {
            const double y0 = (double)y[j*3+0];
            const double y1 = (double)y[j*3+1];
            const double y2 = (double)y[j*3+2];
            v = make_float4((float)(-2.0*y0), (float)(-2.0*y1), (float)(-2.0*y2),
                            (float)(y0*y0 + y1*y1 + y2*y2));
        } else {
            v = make_float4(0.0f, 0.0f, 0.0f, __builtin_inff());
        }
        reinterpret_cast<float4*>(ypad)[p] = v;
    }

    for (int j = tid; j < M_ATM; j += stride) {
        const int bcur  = yb[j];
        const int bprev = (j == 0) ? -1 : yb[j-1];
        for (int t = bprev+1; t <= bcur; ++t) seg[t] = j;
        if (j == M_ATM-1) { for (int t = bcur+1; t <= BB; ++t) seg[t] = M_ATM; }
    }
}

__device__ __forceinline__ unsigned wave_min_u32(unsigned v) {
    #define SW(OFF) { const unsigned o = (unsigned)__builtin_amdgcn_ds_swizzle((int)v, OFF); v = (o < v) ? o : v; }
    SW(0x041F) SW(0x081F) SW(0x101F) SW(0x201F) SW(0x401F)
    #undef SW
    { const unsigned o = (unsigned)__shfl_xor((int)v, 32); v = (o < v) ? o : v; }
    return v;
}

// ---------------- KNN: one WAVE per point, u32 truncated-key selection ----------
__global__ __launch_bounds__(256) void knn_kernel(
    const float* __restrict__ x, const int* __restrict__ xb,
    const float* __restrict__ ypad, const int* __restrict__ seg,
    const float* __restrict__ yg,
    int* __restrict__ out_idx, float* __restrict__ out_d2)
{
    const int wv   = threadIdx.x >> 6;
    const int lane = threadIdx.x & 63;
    const int n    = blockIdx.x * 4 + wv;

    const float xf0 = x[n*3+0], xf1 = x[n*3+1], xf2 = x[n*3+2];
    const float sxf = fmaf(xf0, xf0, fmaf(xf1, xf1, xf2*xf2));
    const int b  = xb[n];
    const int lo = seg[b];
    const float4* __restrict__ base =
        reinterpret_cast<const float4*>(ypad) + b*PSLOT + lane;

    // per-lane sorted top-4 keys via unconditional min/max network
    unsigned m0 = SENT, m1 = SENT, m2 = SENT, m3 = SENT;
    #pragma unroll
    for (int s = 0; s < SLOTS; ++s) {
        const float4 q = base[64*s];
        float dd = fmaf(xf2, q.z, fmaf(xf1, q.y, fmaf(xf0, q.x, sxf + q.w)));
        dd = fmaxf(dd, 0.0f);
        const unsigned kb = (__float_as_uint(dd) & 0xFFFFF000u)
                          | (unsigned)(lane | (s << 6));
        const unsigned a0 = min(m0, kb), c0 = max(m0, kb);
        const unsigned a1 = min(m1, c0), c1 = max(m1, c0);
        const unsigned a2 = min(m2, c1), c2 = max(m2, c1);
        const unsigned a3 = min(m3, c2);
        m0 = a0; m1 = a1; m2 = a2; m3 = a3;
    }

    unsigned long long cmask = 0ull;   // consumed slots (for rare rebuild)
    unsigned res_key = 0, h16 = 0;

    #define POPWIN(H)                                                         \
        if (lane == ((H) & 63u)) {                                            \
            cmask |= 1ull << (((H) >> 6) & 63u);                              \
            m0 = m1; m1 = m2; m2 = m3; m3 = SENT;                             \
            if (m0 == SENT) {                                                 \
                _Pragma("unroll 1")                                           \
                for (int s2 = 0; s2 < SLOTS; ++s2) {                          \
                    const float4 q2 = base[64*s2];                            \
                    float d2f = fmaf(xf2, q2.z, fmaf(xf1, q2.y,               \
                                 fmaf(xf0, q2.x, sxf + q2.w)));               \
                    d2f = fmaxf(d2f, 0.0f);                                   \
                    unsigned kb2 = (__float_as_uint(d2f) & 0xFFFFF000u)       \
                                 | (unsigned)(lane | (s2 << 6));              \
                    if ((cmask >> s2) & 1ull) kb2 = SENT;                     \
                    const unsigned a0 = min(m0, kb2), c0 = max(m0, kb2);      \
                    const unsigned a1 = min(m1, c0), c1 = max(m1, c0);        \
                    const unsigned a2 = min(m2, c1), c2 = max(m2, c1);        \
                    const unsigned a3 = min(m3, c2);                          \
                    m0 = a0; m1 = a1; m2 = a2; m3 = a3;                       \
                }                                                             \
            }                                                                 \
        }

    for (int r = 0; r < KK; ++r) {
        const unsigned h = wave_min_u32(m0);   // wave-uniform winner key
        if (lane == r) res_key = h;
        h16 = h;
        POPWIN(h)
    }

    // margin extras: truncation (2^-11 rel) + f32 eval error coverage
    int e = 0;
    {
        const float d16t = __uint_as_float(h16 & 0xFFFFF000u);
        const unsigned limbits = __float_as_uint(fmaf(d16t, 1.0025f, 0.01f));
        while (e < 8) {
            const unsigned h = wave_min_u32(m0);
            if ((h & 0xFFFFF000u) > limbits) break;
            if (lane == KK + e) res_key = h;
            POPWIN(h)
            ++e;
        }
    }
    #undef POPWIN

    // finalize: exact f64 distances for the 16+e survivors
    const int nact = KK + e;
    const bool have = (lane < nact);
    const unsigned off = res_key & 0xFFFu;
    double dd64 = 0.0;
    if (have) {
        const int j = lo + (int)off;
        const double yy0 = (double)yg[j*3+0];
        const double yy1 = (double)yg[j*3+1];
        const double yy2 = (double)yg[j*3+2];
        const double xd0 = (double)xf0, xd1 = (double)xf1, xd2 = (double)xf2;
        const double sxd = fma(xd0, xd0, fma(xd1, xd1, xd2*xd2));
        const double syd = fma(yy0, yy0, fma(yy1, yy1, yy2*yy2));
        dd64 = fma(xd2, -2.0*yy2, fma(xd1, -2.0*yy1, fma(xd0, -2.0*yy0, sxd + syd)));
        dd64 = fmax(dd64, 0.0);
    }

    if (e == 0) {
        if (have) {
            out_idx[n*KK + lane] = lo + (int)off;
            out_d2 [n*KK + lane] = (float)dd64;
        }
    } else {
        const unsigned long long fkey = have
            ? (((unsigned long long)__double_as_longlong(dd64) & ~0xFFFull) | off)
            : 0xFFFFFFFFFFFFFFFFull;
        int rank = 0;
        #pragma unroll 1
        for (int t = 0; t < nact; ++t) {
            const unsigned klo = (unsigned)__builtin_amdgcn_readlane((int)(unsigned)fkey, t);
            const unsigned khi = (unsigned)__builtin_amdgcn_readlane((int)(unsigned)(fkey >> 32), t);
            const unsigned long long kt = ((unsigned long long)khi << 32) | klo;
            rank += (kt < fkey) ? 1 : 0;
        }
        if (have && rank < KK) {
            out_idx[n*KK + rank] = lo + (int)off;
            out_d2 [n*KK + rank] = (float)dd64;
        }
    }
}

// ---------------- MP: 16 lanes/point, cooperative base + hsum-first W2 ----------
// __launch_bounds__(256, 1): grid supplies only ~4.9 waves/SIMD, so let the
// register allocator use the whole VGPR file (keep w2r/at/pe RESIDENT instead
// of re-loading them inside the o-loop -- the R9-R14 stall signature).
#define DOT16(res, A, q0, q1, q2, q3) {                                 \
    float _e = res, _o = 0.0f;                                          \
    _e = fmaf(A[0],  q0.x, _e); _o = fmaf(A[1],  q0.y, _o);             \
    _e = fmaf(A[2],  q0.z, _e); _o = fmaf(A[3],  q0.w, _o);             \
    _e = fmaf(A[4],  q1.x, _e); _o = fmaf(A[5],  q1.y, _o);             \
    _e = fmaf(A[6],  q1.z, _e); _o = fmaf(A[7],  q1.w, _o);             \
    _e = fmaf(A[8],  q2.x, _e); _o = fmaf(A[9],  q2.y, _o);             \
    _e = fmaf(A[10], q2.z, _e); _o = fmaf(A[11], q2.w, _o);             \
    _e = fmaf(A[12], q3.x, _e); _o = fmaf(A[13], q3.y, _o);             \
    _e = fmaf(A[14], q3.z, _e); _o = fmaf(A[15], q3.w, _o);             \
    res = _e + _o; }

__global__ __launch_bounds__(256, 1) void mp_kernel(
    const int*   __restrict__ nidx, const float* __restrict__ nd2,
    const float* __restrict__ yat,  const float* __restrict__ wpack,
    const float* __restrict__ b2,
    const float* __restrict__ gnw, const float* __restrict__ gnb,
    float* __restrict__ out)
{
    const int g  = blockIdx.x * 256 + threadIdx.x;
    const int n  = g >> 4;
    const int kl = g & 15;     // lane's k AND lane's output channel

    const int   idx  = nidx[n*KK + kl];
    const float dist = nd2 [n*KK + kl];

    float at[DD];
    {
        const float4* p0 = reinterpret_cast<const float4*>(yat + (long)idx*DD);
        const float4 a = p0[0], b = p0[1], c = p0[2], d = p0[3];
        at[0]=a.x;  at[1]=a.y;  at[2]=a.z;  at[3]=a.w;
        at[4]=b.x;  at[5]=b.y;  at[6]=b.z;  at[7]=b.w;
        at[8]=c.x;  at[9]=c.y;  at[10]=c.z; at[11]=c.w;
        at[12]=d.x; at[13]=d.y; at[14]=d.z; at[15]=d.w;
    }

    float pe[DD];
    #pragma unroll
    for (int h = 0; h < DD; ++h) pe[h] = 1.0f;
    float pe_own = 1.0f;

    for (int L = 0; L < 3; ++L) {
        const float* wx = wpack + L*PK_LAY + PK_WX;   // [o][20]
        const float* wb = wpack + L*PK_LAY + PK_WB;   // [o][16] (uniform use)
        const float* wt = wpack + L*PK_LAY + PK_WT;   // [o][16] (col kl per lane)

        // W2 column for own channel: w2r[o] = W2[kl][o]  (coalesced dword loads)
        float w2r[HH];
        #pragma unroll
        for (int o = 0; o < HH; ++o) w2r[o] = wt[o*16 + kl];

        // cooperative base: lane owns rows kl and kl+16; row 32 uniform
        float baseA, baseB, base32;
        {
            const float4* ra = reinterpret_cast<const float4*>(wx + kl*20);
            const float4 a0 = ra[0], a1 = ra[1], a2 = ra[2], a3 = ra[3], a4 = ra[4];
            float t = a4.x; DOT16(t, pe, a0, a1, a2, a3); baseA = t;
            const float4* rb = reinterpret_cast<const float4*>(wx + (kl+16)*20);
            const float4 b0 = rb[0], b1_ = rb[1], b2_ = rb[2], b3 = rb[3], b4 = rb[4];
            t = b4.x; DOT16(t, pe, b0, b1_, b2_, b3); baseB = t;
            const float4* rc = reinterpret_cast<const float4*>(wx + 32*20);
            const float4 c0 = rc[0], c1 = rc[1], c2 = rc[2], c3 = rc[3], c4 = rc[4];
            t = c4.x; DOT16(t, pe, c0, c1, c2, c3); base32 = t;
        }

        float msg_d = 16.0f * b2[L*DD + kl];

        #pragma unroll
        for (int o = 0; o < HH; ++o) {
            float bo;
            if      (o < 16) bo = __shfl(baseA, o,      16);
            else if (o < 32) bo = __shfl(baseB, o - 16, 16);
            else             bo = base32;
            const float wd = wx[o*20 + 17];                       // uniform
            const float4* wr = reinterpret_cast<const float4*>(wb + o*16);
            const float4 y0 = wr[0], y1 = wr[1], y2 = wr[2], y3 = wr[3];
            float u = fmaf(dist, wd, bo);
            DOT16(u, at, y0, y1, y2, y3);
            float hs = fmaxf(u, SLOPE*u);          // leaky per-k
            hs += __shfl_xor(hs, 1, 16);           // sum over the point's 16 k's
            hs += __shfl_xor(hs, 2, 16);
            hs += __shfl_xor(hs, 4, 16);
            hs += __shfl_xor(hs, 8, 16);
            msg_d = fmaf(hs, w2r[o], msg_d);       // own channel only
        }

        // GroupNorm(2,16): lane owns channel kl; group = kl>>3 (8 lanes)
        float s = msg_d;
        s += __shfl_xor(s, 1, 16); s += __shfl_xor(s, 2, 16); s += __shfl_xor(s, 4, 16);
        const float mu = s * 0.125f;
        const float dvn = msg_d - mu;
        float v2 = dvn * dvn;
        v2 += __shfl_xor(v2, 1, 16); v2 += __shfl_xor(v2, 2, 16); v2 += __shfl_xor(v2, 4, 16);
        const float rs = rsqrtf(v2 * 0.125f + EPSGN);
        const float v = dvn * rs * gnw[L*DD + kl] + gnb[L*DD + kl];
        pe_own += fmaxf(v, SLOPE * v);

        // rebuild replicated pe[16] for next layer's base phase
        #pragma unroll
        for (int j = 0; j < DD; ++j) pe[j] = __shfl(pe_own, j, 16);
    }

    if (kl == 0) {
        float4* op = reinterpret_cast<float4*>(out + (long)n*DD);
        op[0] = make_float4(pe[0],  pe[1],  pe[2],  pe[3]);
        op[1] = make_float4(pe[4],  pe[5],  pe[6],  pe[7]);
        op[2] = make_float4(pe[8],  pe[9],  pe[10], pe[11]);
        op[3] = make_float4(pe[12], pe[13], pe[14], pe[15]);
    }
}

extern "C" void kernel_launch(void* const* d_in, const int* in_sizes, int n_in,
                              void* d_out, int out_size, void* d_ws, size_t ws_size,
                              hipStream_t stream) {
    const float* x   = (const float*)d_in[0];
    const float* y   = (const float*)d_in[1];
    const float* yat = (const float*)d_in[2];
    const int*   xb  = (const int*)  d_in[3];
    const int*   yb  = (const int*)  d_in[4];
    const float* W1  = (const float*)d_in[5];
    const float* b1  = (const float*)d_in[6];
    const float* W2  = (const float*)d_in[7];
    const float* b2  = (const float*)d_in[8];
    const float* gnw = (const float*)d_in[9];
    const float* gnb = (const float*)d_in[10];
    float* out = (float*)d_out;

    float* ypad   = (float*)((char*)d_ws + WS_PAD);
    int*   seg    = (int*)  ((char*)d_ws + WS_SEG);
    float* wpack  = (float*)((char*)d_ws + WS_WP);
    int*   ws_idx = (int*)  ((char*)d_ws + WS_IDX);
    float* ws_d2  = (float*)((char*)d_ws + WS_D2);

    repack_kernel<<<16, 256, 0, stream>>>(W1, b1, W2, y, yb, wpack, ypad, seg);
    knn_kernel<<<N_PTS/4, 256, 0, stream>>>(x, xb, ypad, seg, y, ws_idx, ws_d2);
    mp_kernel<<<(N_PTS*16)/256, 256, 0, stream>>>(
        ws_idx, ws_d2, yat, wpack, b2, gnw, gnb, out);
}

// Round 17
// 76.055 us; speedup vs baseline: 1.3480x; 1.1696x over previous
//
#include <hip/hip_runtime.h>
#include <math.h>

#define N_PTS 20000
#define M_ATM 8000
#define DD    16
#define KK    16
#define HH    33
#define BB    4
#define EPSGN 1e-5f
#define SLOPE 0.2f
#define SLOTS 36          // 36*64 = 2304 candidate slots per batch
#define PSLOT 2304
#define SENT  0xFFFFFFFFu // > any real key (real off <= 2303 < 0xFFF)

// packed layout per layer (floats): wx[33][20] | wb[33][16] | wt[33][16]
#define PK_WX   0
#define PK_WB   660
#define PK_WT   1188
#define PK_LAY  1716

// ws layout (bytes)
#define WS_PAD   0                      // 4*2304*16 = 147456 (padded f32 atom table)
#define WS_SEG   147456                 // 8 ints
#define WS_WP    147520                 // 3*1716 floats -> ends 168112
#define WS_IDX   168128                 // N*K ints
#define WS_D2    (168128 + 1280000)     // N*K floats

// ---- DPP cross-lane helpers (VALU pipe, ~4cyc latency vs ~35 for ds_swizzle) ----
// ctrl must be a compile-time constant -> template parameter.
template<int CTRL> __device__ __forceinline__ float dpp_addf(float v) {
    return v + __int_as_float(__builtin_amdgcn_update_dpp(
        0, __float_as_int(v), CTRL, 0xF, 0xF, true));
}
__device__ __forceinline__ float dpp_sum16(float v) {
    v = dpp_addf<0xB1>(v);    // quad_perm [1,0,3,2]  (xor 1)
    v = dpp_addf<0x4E>(v);    // quad_perm [2,3,0,1]  (xor 2)
    v = dpp_addf<0x141>(v);   // row_half_mirror      (merge quads within 8)
    v = dpp_addf<0x140>(v);   // row_mirror           (merge halves within 16)
    return v;
}
__device__ __forceinline__ float dpp_sum8(float v) {
    v = dpp_addf<0xB1>(v);
    v = dpp_addf<0x4E>(v);
    v = dpp_addf<0x141>(v);
    return v;
}
// broadcast lane O (0..15) within each 16-lane group (BitMode swizzle)
template<int O> __device__ __forceinline__ float bc16(float v) {
    return __int_as_float(__builtin_amdgcn_ds_swizzle(
        __float_as_int(v), (O << 5) | 0x10));
}
template<int CTRL> __device__ __forceinline__ unsigned dpp_min_u32(unsigned v) {
    const unsigned o = (unsigned)__builtin_amdgcn_update_dpp(
        (int)v, (int)v, CTRL, 0xF, 0xF, false);
    return (o < v) ? o : v;
}

// ---------------- repack: weights + padded f32 atom table + batch boundaries ----
__global__ void repack_kernel(const float* __restrict__ W1, const float* __restrict__ b1,
                              const float* __restrict__ W2,
                              const float* __restrict__ y, const int* __restrict__ yb,
                              float* __restrict__ wp, float* __restrict__ ypad,
                              int* __restrict__ seg)
{
    const int tid = blockIdx.x*256 + threadIdx.x;
    const int stride = gridDim.x*256;

    for (int i = tid; i < 3*PK_LAY; i += stride) {
        const int L = i / PK_LAY, r = i % PK_LAY;
        float v;
        if (r < PK_WB) {                    // wx[o][20] = W1a(16) | b1 | w_dist | pad2
            const int o = r / 20, c = r % 20;
            if      (c < 16)  v = W1[(L*HH + o)*HH + c];
            else if (c == 16) v = b1[L*HH + o];
            else if (c == 17) v = W1[(L*HH + o)*HH + 32];
            else              v = 0.0f;
        } else if (r < PK_WT) {             // wb[o][16] = W1[o][16..31]
            const int q = r - PK_WB, o = q / 16, c = q % 16;
            v = W1[(L*HH + o)*HH + 16 + c];
        } else {                            // wt[o][16] = W2[d][o] transposed
            const int q = r - PK_WT, o = q / 16, d = q % 16;
            v = W2[(L*DD + d)*HH + o];
        }
        wp[i] = v;
    }

    // padded candidate table: [b][slot] = (-2y0,-2y1,-2y2,|y|^2), pad = +inf
    for (int p = tid; p < BB*PSLOT; p += stride) {
        const int b = p / PSLOT, o = p % PSLOT;
        int l = 0, r = M_ATM;
        while (l < r) { int m = (l+r) >> 1; if (yb[m] <  b) l = m+1; else r = m; }
        const int lo = l;
        l = 0; r = M_ATM;
        while (l < r) { int m = (l+r) >> 1; if (yb[m] <= b) l = m+1; else r = m; }
        const int hi = l;
        float4 v;
        const int j = lo + o;
        if (j < hi) {
            const double y0 = (double)y[j*3+0];
            const double y1 = (double)y[j*3+1];
            const double y2 = (double)y[j*3+2];
            v = make_float4((float)(-2.0*y0), (float)(-2.0*y1), (float)(-2.0*y2),
                            (float)(y0*y0 + y1*y1 + y2*y2));
        } else {
            v = make_float4(0.0f, 0.0f, 0.0f, __builtin_inff());
        }
        reinterpret_cast<float4*>(ypad)[p] = v;
    }

    for (int j = tid; j < M_ATM; j += stride) {
        const int bcur  = yb[j];
        const int bprev = (j == 0) ? -1 : yb[j-1];
        for (int t = bprev+1; t <= bcur; ++t) seg[t] = j;
        if (j == M_ATM-1) { for (int t = bcur+1; t <= BB; ++t) seg[t] = M_ATM; }
    }
}

__device__ __forceinline__ unsigned wave_min_u32(unsigned v) {
    v = dpp_min_u32<0xB1>(v);    // xor 1  (VALU)
    v = dpp_min_u32<0x4E>(v);    // xor 2  (VALU)
    v = dpp_min_u32<0x141>(v);   // 8-lane merge (VALU)
    v = dpp_min_u32<0x140>(v);   // 16-lane merge (VALU)
    { const unsigned o = (unsigned)__builtin_amdgcn_ds_swizzle((int)v, 0x401F);  // xor 16
      v = (o < v) ? o : v; }
    { const unsigned o = (unsigned)__shfl_xor((int)v, 32);                        // xor 32
      v = (o < v) ? o : v; }
    return v;
}

// ---------------- KNN: one WAVE per point, u32 truncated-key selection ----------
__global__ __launch_bounds__(256) void knn_kernel(
    const float* __restrict__ x, const int* __restrict__ xb,
    const float* __restrict__ ypad, const int* __restrict__ seg,
    const float* __restrict__ yg,
    int* __restrict__ out_idx, float* __restrict__ out_d2)
{
    const int wv   = threadIdx.x >> 6;
    const int lane = threadIdx.x & 63;
    const int n    = blockIdx.x * 4 + wv;

    const float xf0 = x[n*3+0], xf1 = x[n*3+1], xf2 = x[n*3+2];
    const float sxf = fmaf(xf0, xf0, fmaf(xf1, xf1, xf2*xf2));
    const int b  = xb[n];
    const int lo = seg[b];
    const float4* __restrict__ base =
        reinterpret_cast<const float4*>(ypad) + b*PSLOT + lane;

    // per-lane sorted top-4 keys via unconditional min/max network
    unsigned m0 = SENT, m1 = SENT, m2 = SENT, m3 = SENT;
    #pragma unroll
    for (int s = 0; s < SLOTS; ++s) {
        const float4 q = base[64*s];
        float dd = fmaf(xf2, q.z, fmaf(xf1, q.y, fmaf(xf0, q.x, sxf + q.w)));
        dd = fmaxf(dd, 0.0f);
        const unsigned kb = (__float_as_uint(dd) & 0xFFFFF000u)
                          | (unsigned)(lane | (s << 6));
        const unsigned a0 = min(m0, kb), c0 = max(m0, kb);
        const unsigned a1 = min(m1, c0), c1 = max(m1, c0);
        const unsigned a2 = min(m2, c1), c2 = max(m2, c1);
        const unsigned a3 = min(m3, c2);
        m0 = a0; m1 = a1; m2 = a2; m3 = a3;
    }

    unsigned long long cmask = 0ull;   // consumed slots (for rare rebuild)
    unsigned res_key = 0, h16 = 0;

    #define POPWIN(H)                                                         \
        if (lane == ((H) & 63u)) {                                            \
            cmask |= 1ull << (((H) >> 6) & 63u);                              \
            m0 = m1; m1 = m2; m2 = m3; m3 = SENT;                             \
            if (m0 == SENT) {                                                 \
                _Pragma("unroll 1")                                           \
                for (int s2 = 0; s2 < SLOTS; ++s2) {                          \
                    const float4 q2 = base[64*s2];                            \
                    float d2f = fmaf(xf2, q2.z, fmaf(xf1, q2.y,               \
                                 fmaf(xf0, q2.x, sxf + q2.w)));               \
                    d2f = fmaxf(d2f, 0.0f);                                   \
                    unsigned kb2 = (__float_as_uint(d2f) & 0xFFFFF000u)       \
                                 | (unsigned)(lane | (s2 << 6));              \
                    if ((cmask >> s2) & 1ull) kb2 = SENT;                     \
                    const unsigned a0 = min(m0, kb2), c0 = max(m0, kb2);      \
                    const unsigned a1 = min(m1, c0), c1 = max(m1, c0);        \
                    const unsigned a2 = min(m2, c1), c2 = max(m2, c1);        \
                    const unsigned a3 = min(m3, c2);                          \
                    m0 = a0; m1 = a1; m2 = a2; m3 = a3;                       \
                }                                                             \
            }                                                                 \
        }

    for (int r = 0; r < KK; ++r) {
        const unsigned h = wave_min_u32(m0);   // wave-uniform winner key
        if (lane == r) res_key = h;
        h16 = h;
        POPWIN(h)
    }

    // margin extras: truncation (2^-11 rel) + f32 eval error coverage
    int e = 0;
    {
        const float d16t = __uint_as_float(h16 & 0xFFFFF000u);
        const unsigned limbits = __float_as_uint(fmaf(d16t, 1.0025f, 0.01f));
        while (e < 8) {
            const unsigned h = wave_min_u32(m0);
            if ((h & 0xFFFFF000u) > limbits) break;
            if (lane == KK + e) res_key = h;
            POPWIN(h)
            ++e;
        }
    }
    #undef POPWIN

    // finalize: exact f64 distances for the 16+e survivors
    const int nact = KK + e;
    const bool have = (lane < nact);
    const unsigned off = res_key & 0xFFFu;
    double dd64 = 0.0;
    if (have) {
        const int j = lo + (int)off;
        const double yy0 = (double)yg[j*3+0];
        const double yy1 = (double)yg[j*3+1];
        const double yy2 = (double)yg[j*3+2];
        const double xd0 = (double)xf0, xd1 = (double)xf1, xd2 = (double)xf2;
        const double sxd = fma(xd0, xd0, fma(xd1, xd1, xd2*xd2));
        const double syd = fma(yy0, yy0, fma(yy1, yy1, yy2*yy2));
        dd64 = fma(xd2, -2.0*yy2, fma(xd1, -2.0*yy1, fma(xd0, -2.0*yy0, sxd + syd)));
        dd64 = fmax(dd64, 0.0);
    }

    if (e == 0) {
        if (have) {
            out_idx[n*KK + lane] = lo + (int)off;
            out_d2 [n*KK + lane] = (float)dd64;
        }
    } else {
        const unsigned long long fkey = have
            ? (((unsigned long long)__double_as_longlong(dd64) & ~0xFFFull) | off)
            : 0xFFFFFFFFFFFFFFFFull;
        int rank = 0;
        #pragma unroll 1
        for (int t = 0; t < nact; ++t) {
            const unsigned klo = (unsigned)__builtin_amdgcn_readlane((int)(unsigned)fkey, t);
            const unsigned khi = (unsigned)__builtin_amdgcn_readlane((int)(unsigned)(fkey >> 32), t);
            const unsigned long long kt = ((unsigned long long)khi << 32) | klo;
            rank += (kt < fkey) ? 1 : 0;
        }
        if (have && rank < KK) {
            out_idx[n*KK + rank] = lo + (int)off;
            out_d2 [n*KK + rank] = (float)dd64;
        }
    }
}

// ---------------- MP: 16 lanes/point, coop base + hsum-first W2, DPP reductions --
#define DOT16(res, A, q0, q1, q2, q3) {                                 \
    float _e = res, _o = 0.0f;                                          \
    _e = fmaf(A[0],  q0.x, _e); _o = fmaf(A[1],  q0.y, _o);             \
    _e = fmaf(A[2],  q0.z, _e); _o = fmaf(A[3],  q0.w, _o);             \
    _e = fmaf(A[4],  q1.x, _e); _o = fmaf(A[5],  q1.y, _o);             \
    _e = fmaf(A[6],  q1.z, _e); _o = fmaf(A[7],  q1.w, _o);             \
    _e = fmaf(A[8],  q2.x, _e); _o = fmaf(A[9],  q2.y, _o);             \
    _e = fmaf(A[10], q2.z, _e); _o = fmaf(A[11], q2.w, _o);             \
    _e = fmaf(A[12], q3.x, _e); _o = fmaf(A[13], q3.y, _o);             \
    _e = fmaf(A[14], q3.z, _e); _o = fmaf(A[15], q3.w, _o);             \
    res = _e + _o; }

__global__ __launch_bounds__(256, 1) void mp_kernel(
    const int*   __restrict__ nidx, const float* __restrict__ nd2,
    const float* __restrict__ yat,  const float* __restrict__ wpack,
    const float* __restrict__ b2,
    const float* __restrict__ gnw, const float* __restrict__ gnb,
    float* __restrict__ out)
{
    const int g  = blockIdx.x * 256 + threadIdx.x;
    const int n  = g >> 4;
    const int kl = g & 15;     // lane's k AND lane's output channel

    const int   idx  = nidx[n*KK + kl];
    const float dist = nd2 [n*KK + kl];

    float at[DD];
    {
        const float4* p0 = reinterpret_cast<const float4*>(yat + (long)idx*DD);
        const float4 a = p0[0], b = p0[1], c = p0[2], d = p0[3];
        at[0]=a.x;  at[1]=a.y;  at[2]=a.z;  at[3]=a.w;
        at[4]=b.x;  at[5]=b.y;  at[6]=b.z;  at[7]=b.w;
        at[8]=c.x;  at[9]=c.y;  at[10]=c.z; at[11]=c.w;
        at[12]=d.x; at[13]=d.y; at[14]=d.z; at[15]=d.w;
    }

    float pe[DD];
    #pragma unroll
    for (int h = 0; h < DD; ++h) pe[h] = 1.0f;
    float pe_own = 1.0f;

    for (int L = 0; L < 3; ++L) {
        const float* wx = wpack + L*PK_LAY + PK_WX;   // [o][20]
        const float* wb = wpack + L*PK_LAY + PK_WB;   // [o][16] (uniform use)
        const float* wt = wpack + L*PK_LAY + PK_WT;   // [o][16] (col kl per lane)

        // W2 column for own channel: w2r[o] = W2[kl][o]
        float w2r[HH];
        #pragma unroll
        for (int o = 0; o < HH; ++o) w2r[o] = wt[o*16 + kl];

        // cooperative base: lane owns rows kl and kl+16; row 32 uniform
        float baseA, baseB, base32;
        {
            const float4* ra = reinterpret_cast<const float4*>(wx + kl*20);
            const float4 a0 = ra[0], a1 = ra[1], a2 = ra[2], a3 = ra[3], a4 = ra[4];
            float t = a4.x; DOT16(t, pe, a0, a1, a2, a3); baseA = t;
            const float4* rb = reinterpret_cast<const float4*>(wx + (kl+16)*20);
            const float4 b0 = rb[0], b1_ = rb[1], b2_ = rb[2], b3 = rb[3], b4 = rb[4];
            t = b4.x; DOT16(t, pe, b0, b1_, b2_, b3); baseB = t;
            const float4* rc = reinterpret_cast<const float4*>(wx + 32*20);
            const float4 c0 = rc[0], c1 = rc[1], c2 = rc[2], c3 = rc[3], c4 = rc[4];
            t = c4.x; DOT16(t, pe, c0, c1, c2, c3); base32 = t;
        }

        // hoisted broadcasts: all independent ds_swizzles, latency overlapped
        float bo[HH];
        #define BC(i) bo[i] = bc16<i>(baseA); bo[16+(i)] = bc16<i>(baseB);
        BC(0)  BC(1)  BC(2)  BC(3)  BC(4)  BC(5)  BC(6)  BC(7)
        BC(8)  BC(9)  BC(10) BC(11) BC(12) BC(13) BC(14) BC(15)
        #undef BC
        bo[32] = base32;

        float msg_d = 16.0f * b2[L*DD + kl];

        // pure-VALU inner loop: dist FMA + at-dot + leaky + 4 DPP adds + W2 FMA
        #pragma unroll
        for (int o = 0; o < HH; ++o) {
            const float wd = wx[o*20 + 17];                       // uniform
            const float4* wr = reinterpret_cast<const float4*>(wb + o*16);
            const float4 y0 = wr[0], y1 = wr[1], y2 = wr[2], y3 = wr[3];
            float u = fmaf(dist, wd, bo[o]);
            DOT16(u, at, y0, y1, y2, y3);
            float hs = fmaxf(u, SLOPE*u);          // leaky per-k
            hs = dpp_sum16(hs);                    // sum over the point's 16 k's
            msg_d = fmaf(hs, w2r[o], msg_d);       // own channel only
        }

        // GroupNorm(2,16): lane owns channel kl; group = kl>>3 (8 lanes, DPP)
        const float mu = dpp_sum8(msg_d) * 0.125f;
        const float dvn = msg_d - mu;
        const float var = dpp_sum8(dvn * dvn) * 0.125f;
        const float rs = rsqrtf(var + EPSGN);
        const float v = dvn * rs * gnw[L*DD + kl] + gnb[L*DD + kl];
        pe_own += fmaxf(v, SLOPE * v);

        // rebuild replicated pe[16] for next layer's base phase
        #define PEB(i) pe[i] = bc16<i>(pe_own);
        PEB(0)  PEB(1)  PEB(2)  PEB(3)  PEB(4)  PEB(5)  PEB(6)  PEB(7)
        PEB(8)  PEB(9)  PEB(10) PEB(11) PEB(12) PEB(13) PEB(14) PEB(15)
        #undef PEB
    }

    if (kl == 0) {
        float4* op = reinterpret_cast<float4*>(out + (long)n*DD);
        op[0] = make_float4(pe[0],  pe[1],  pe[2],  pe[3]);
        op[1] = make_float4(pe[4],  pe[5],  pe[6],  pe[7]);
        op[2] = make_float4(pe[8],  pe[9],  pe[10], pe[11]);
        op[3] = make_float4(pe[12], pe[13], pe[14], pe[15]);
    }
}

extern "C" void kernel_launch(void* const* d_in, const int* in_sizes, int n_in,
                              void* d_out, int out_size, void* d_ws, size_t ws_size,
                              hipStream_t stream) {
    const float* x   = (const float*)d_in[0];
    const float* y   = (const float*)d_in[1];
    const float* yat = (const float*)d_in[2];
    const int*   xb  = (const int*)  d_in[3];
    const int*   yb  = (const int*)  d_in[4];
    const float* W1  = (const float*)d_in[5];
    const float* b1  = (const float*)d_in[6];
    const float* W2  = (const float*)d_in[7];
    const float* b2  = (const float*)d_in[8];
    const float* gnw = (const float*)d_in[9];
    const float* gnb = (const float*)d_in[10];
    float* out = (float*)d_out;

    float* ypad   = (float*)((char*)d_ws + WS_PAD);
    int*   seg    = (int*)  ((char*)d_ws + WS_SEG);
    float* wpack  = (float*)((char*)d_ws + WS_WP);
    int*   ws_idx = (int*)  ((char*)d_ws + WS_IDX);
    float* ws_d2  = (float*)((char*)d_ws + WS_D2);

    repack_kernel<<<16, 256, 0, stream>>>(W1, b1, W2, y, yb, wpack, ypad, seg);
    knn_kernel<<<N_PTS/4, 256, 0, stream>>>(x, xb, ypad, seg, y, ws_idx, ws_d2);
    mp_kernel<<<(N_PTS*16)/256, 256, 0, stream>>>(
        ws_idx, ws_d2, yat, wpack, b2, gnw, gnb, out);
}